// Round 16
// baseline (284.835 us; speedup 1.0000x reference)
//
#include <hip/hip_runtime.h>
#include <hip/hip_bf16.h>

typedef __attribute__((ext_vector_type(8))) short bf16x8;
typedef __attribute__((ext_vector_type(4))) float f32x4;

// ---------------- helpers ----------------
__device__ inline float wave_sum64(float v) {
#pragma unroll
  for (int m = 32; m >= 1; m >>= 1) v += __shfl_xor(v, m, 64);
  return v;
}
__device__ inline ushort f2bf(float f) {  // RNE float->bf16
  uint u = __float_as_uint(f);
  return (ushort)((u + 0x7FFFu + ((u >> 16) & 1u)) >> 16);
}

// ---------------- weight pack + starts/meta + input projection (one dispatch) ----------------
__global__ __launch_bounds__(256) void pack_inproj(
    const float* __restrict__ qkv_w, const float* __restrict__ out_w,
    const float* __restrict__ ff1_w, const float* __restrict__ ff2_w,
    const float* __restrict__ b1_w, const float* __restrict__ lat_w,
    short* __restrict__ qkv_t, short* __restrict__ out_t,
    short* __restrict__ ff1_t, short* __restrict__ ff2_t,
    short* __restrict__ b1_t, short* __restrict__ lat_t,
    const int* __restrict__ batch, int* __restrict__ starts, int* __restrict__ meta,
    const float* __restrict__ x, const float* __restrict__ Wi,
    const float* __restrict__ bi, float* __restrict__ h, short* __restrict__ hb) {
  int t = blockIdx.x;
  __shared__ float tile[32][33];

  if (t >= 3113) {  // input projection: one row per block
    const int row = t - 3113;
    const int j = threadIdx.x;
    float* xs = &tile[0][0];
    if (j < 16) xs[j] = x[(size_t)row * 16 + j];
    __syncthreads();
    float acc = bi[j];
#pragma unroll
    for (int k = 0; k < 16; ++k) acc += xs[k] * Wi[k * 256 + j];
    h[(size_t)row * 256 + j] = acc;
    hb[(size_t)row * 256 + j] = (short)f2bf(acc);
    return;
  }
  if (t == 3112) {  // graph boundaries + graph-aligned 16-row tile list
    for (int i = threadIdx.x; i < 2048; i += 256) {
      int b = batch[i];
      if (i == 0) {
        for (int g = 0; g <= b; ++g) starts[g] = 0;
      } else {
        int bp = batch[i - 1];
        for (int g = bp + 1; g <= b; ++g) starts[g] = i;
      }
      if (i == 2047) {
        for (int g = b + 1; g <= 16; ++g) starts[g] = 2048;
      }
    }
    __syncthreads();
    if (threadIdx.x == 0) {
      int nt = 0;
      for (int g = 0; g < 16; ++g) {
        const int js = starts[g], je = starts[g + 1];
        for (int q0 = js; q0 < je; q0 += 16) {
          meta[1 + nt * 3] = q0;
          meta[2 + nt * 3] = js;
          meta[3 + nt * 3] = je;
          ++nt;
        }
      }
      meta[0] = nt;
    }
    return;
  }
  const float* src;
  short* dst;
  int Kd, Nd, rem;
  if (t < 768) {
    int l = t / 192; rem = t % 192; Kd = 256; Nd = 768;
    src = qkv_w + (size_t)l * Kd * Nd; dst = qkv_t + (size_t)l * Nd * Kd;
  } else if (t < 1024) {
    t -= 768; int l = t / 64; rem = t % 64; Kd = 256; Nd = 256;
    src = out_w + (size_t)l * Kd * Nd; dst = out_t + (size_t)l * Nd * Kd;
  } else if (t < 2048) {
    t -= 1024; int l = t / 256; rem = t % 256; Kd = 256; Nd = 1024;
    src = ff1_w + (size_t)l * Kd * Nd; dst = ff1_t + (size_t)l * Nd * Kd;
  } else if (t < 3072) {
    t -= 2048; int l = t / 256; rem = t % 256; Kd = 1024; Nd = 256;
    src = ff2_w + (size_t)l * Kd * Nd; dst = ff2_t + (size_t)l * Nd * Kd;
  } else if (t < 3104) {
    rem = t - 3072; Kd = 256; Nd = 128; src = b1_w; dst = b1_t;
  } else {
    rem = t - 3104; Kd = 256; Nd = 32; src = lat_w; dst = lat_t;
  }
  const int ntn = Nd / 32;
  const int kt = rem / ntn, nt = rem % ntn;
  const int tx = threadIdx.x & 31, ty = threadIdx.x >> 5;
#pragma unroll
  for (int r = 0; r < 4; ++r) {
    int k = kt * 32 + ty + r * 8;
    tile[ty + r * 8][tx] = src[(size_t)k * Nd + nt * 32 + tx];
  }
  __syncthreads();
#pragma unroll
  for (int r = 0; r < 4; ++r) {
    int n = nt * 32 + ty + r * 8;
    dst[(size_t)n * Kd + kt * 32 + tx] = (short)f2bf(tile[tx][ty + r * 8]);
  }
}

// ---------------- MFMA bf16 GEMM, BK=128 (r11-proven; used for qkv only) ----------------
// bf16 out for Q,K; V cols (bn>=8) go ONLY to V^T [256][2048] via LDS transpose.
__global__ __launch_bounds__(256) void gemm_qkv(
    const short* __restrict__ A, const short* __restrict__ Bt,
    const float* __restrict__ bias, short* __restrict__ Cb,
    short* __restrict__ vtg, int N, int K) {
  __shared__ short As[64 * 128];
  __shared__ short Bs[64 * 128];

  const int t = threadIdx.x;
  const int bm = blockIdx.y, bn = blockIdx.x;
  const int srow = t >> 2, sq = t & 3;
  const int lane = t & 63, wid = t >> 6;
  const int wr = wid >> 1, wc = wid & 1;
  const int fr = lane & 15, fs = lane >> 4;
  const int rx = srow & 7;

  f32x4 acc[2][2];
#pragma unroll
  for (int m = 0; m < 2; ++m)
#pragma unroll
    for (int n = 0; n < 2; ++n) acc[m][n] = (f32x4){0.f, 0.f, 0.f, 0.f};

  const short* ap = A + (size_t)(bm * 64 + srow) * K;
  const int ng = bn * 64 + srow;
  const short* bp = Bt + (size_t)ng * K;
  const int ar0 = wr * 32 + fr, ar1 = ar0 + 16;
  const int bc0 = wc * 32 + fr, bc1 = bc0 + 16;

  for (int k0 = 0; k0 < K; k0 += 128) {
    bf16x8 av[4], bv[4];
#pragma unroll
    for (int i = 0; i < 4; ++i) av[i] = *(const bf16x8*)(ap + k0 + (sq * 4 + i) * 8);
#pragma unroll
    for (int i = 0; i < 4; ++i) bv[i] = *(const bf16x8*)(bp + k0 + (sq * 4 + i) * 8);
    __syncthreads();
#pragma unroll
    for (int i = 0; i < 4; ++i) {
      const int s = sq * 4 + i;
      *(bf16x8*)(As + srow * 128 + ((s ^ rx) * 8)) = av[i];
      *(bf16x8*)(Bs + srow * 128 + ((s ^ rx) * 8)) = bv[i];
    }
    __syncthreads();
#pragma unroll
    for (int ks = 0; ks < 4; ++ks) {
      const int u = ks * 4 + fs;
      bf16x8 a0 = *(const bf16x8*)(As + ar0 * 128 + ((u ^ (ar0 & 7)) * 8));
      bf16x8 a1 = *(const bf16x8*)(As + ar1 * 128 + ((u ^ (ar1 & 7)) * 8));
      bf16x8 b0 = *(const bf16x8*)(Bs + bc0 * 128 + ((u ^ (bc0 & 7)) * 8));
      bf16x8 b1 = *(const bf16x8*)(Bs + bc1 * 128 + ((u ^ (bc1 & 7)) * 8));
      acc[0][0] = __builtin_amdgcn_mfma_f32_16x16x32_bf16(a0, b0, acc[0][0], 0, 0, 0);
      acc[0][1] = __builtin_amdgcn_mfma_f32_16x16x32_bf16(a0, b1, acc[0][1], 0, 0, 0);
      acc[1][0] = __builtin_amdgcn_mfma_f32_16x16x32_bf16(a1, b0, acc[1][0], 0, 0, 0);
      acc[1][1] = __builtin_amdgcn_mfma_f32_16x16x32_bf16(a1, b1, acc[1][1], 0, 0, 0);
    }
  }

  if (bn < 8) {  // Q,K columns -> bf16
#pragma unroll
    for (int n = 0; n < 2; ++n) {
      const int col = bn * 64 + wc * 32 + n * 16 + fr;
      const float bvv = bias[col];
#pragma unroll
      for (int m = 0; m < 2; ++m) {
        const int rbase = bm * 64 + wr * 32 + m * 16 + fs * 4;
#pragma unroll
        for (int j = 0; j < 4; ++j) {
          Cb[(size_t)(rbase + j) * N + col] = (short)f2bf(acc[m][n][j] + bvv);
        }
      }
    }
  } else {  // V columns -> coalesced V^T
    short* tr = As;  // reuse LDS: [64 cols][68 rows]
    __syncthreads();
#pragma unroll
    for (int n = 0; n < 2; ++n) {
      const int c = wc * 32 + n * 16 + fr;
      const float bvv = bias[bn * 64 + c];
#pragma unroll
      for (int m = 0; m < 2; ++m)
#pragma unroll
        for (int j = 0; j < 4; ++j) {
          const int r = wr * 32 + m * 16 + fs * 4 + j;
          tr[c * 68 + r] = (short)f2bf(acc[m][n][j] + bvv);
        }
    }
    __syncthreads();
    const int tx = t & 63, ty = t >> 6;
    const int d0 = bn * 64 - 512, rb = bm * 64;
#pragma unroll
    for (int r = 0; r < 16; ++r) {
      const int d = ty * 16 + r;
      vtg[(size_t)(d0 + d) * 2048 + rb + tx] = tr[d * 68 + tx];
    }
  }
}

// ---------------- attention + full out-proj + residual + LN1, one block per q-tile ----------------
// 512 threads = 8 waves; wave w = head w (r15-proven). O -> Ot LDS; barrier; each wave
// does 2 col-tiles of out-proj at full K=256; block applies residual + LN via LDS reduce.
__global__ __launch_bounds__(512) void attn_fused(
    const short* __restrict__ qkv, const short* __restrict__ vtg,
    const int* __restrict__ meta, const short* __restrict__ out_t,
    const float* __restrict__ outb, const float* __restrict__ lns,
    const float* __restrict__ lnb, float* __restrict__ h, short* __restrict__ hb) {
  __shared__ short Ot[8][16][40];
  __shared__ float redS[8][16], redQ[8][16];
  const int w = threadIdx.x >> 6;  // wave = head
  const int tile = blockIdx.x;
  const bool active = (tile < meta[0]);
  const int lane = threadIdx.x & 63;
  const int fr = lane & 15, fs = lane >> 4;
  const int q0 = active ? meta[1 + tile * 3] : 0;
  const int js = active ? meta[2 + tile * 3] : 0;
  const int je = active ? meta[3 + tile * 3] : 0;
  const int jbase = js & ~15;
  const int njt = active ? ((je - jbase + 15) >> 4) : 0;  // <=16
  const float scale = 0.17677669529663687f;  // 1/sqrt(32)

  const int qrow = min(q0 + fr, 2047);
  const bf16x8 qf = *(const bf16x8*)(qkv + (size_t)qrow * 768 + w * 32 + fs * 8);
  const int jeq = (q0 + fr < je) ? je : 0;

  f32x4 s[16];
#pragma unroll
  for (int jt = 0; jt < 16; ++jt)
    s[jt] = (f32x4){-3.0e38f, -3.0e38f, -3.0e38f, -3.0e38f};

#pragma unroll
  for (int jt = 0; jt < 16; ++jt) {
    if (jt < njt) {
      const int krow = min(jbase + jt * 16 + fr, 2047);
      const bf16x8 kf = *(const bf16x8*)(qkv + (size_t)krow * 768 + 256 + w * 32 + fs * 8);
      s[jt] = __builtin_amdgcn_mfma_f32_16x16x32_bf16(
          kf, qf, (f32x4){0.f, 0.f, 0.f, 0.f}, 0, 0, 0);
    }
  }
  float mx = -3.0e38f;
#pragma unroll
  for (int jt = 0; jt < 16; ++jt) {
    if (jt < njt) {
#pragma unroll
      for (int jj = 0; jj < 4; ++jj) {
        const int j = jbase + jt * 16 + fs * 4 + jj;
        const bool valid = (j >= js) && (j < jeq);
        s[jt][jj] = valid ? s[jt][jj] * scale : -3.0e38f;
        mx = fmaxf(mx, s[jt][jj]);
      }
    }
  }
  mx = fmaxf(mx, __shfl_xor(mx, 16, 64));
  mx = fmaxf(mx, __shfl_xor(mx, 32, 64));
  float l = 0.f;
#pragma unroll
  for (int jt = 0; jt < 16; ++jt) {
#pragma unroll
    for (int jj = 0; jj < 4; ++jj) {
      const float p = __expf(s[jt][jj] - mx);
      s[jt][jj] = p;
      l += p;
    }
  }
  l += __shfl_xor(l, 16, 64);
  l += __shfl_xor(l, 32, 64);

  f32x4 oa[2];
  oa[0] = (f32x4){0.f, 0.f, 0.f, 0.f};
  oa[1] = (f32x4){0.f, 0.f, 0.f, 0.f};
#pragma unroll
  for (int p2 = 0; p2 < 8; ++p2) {
    if (p2 * 2 < njt) {
      bf16x8 pa;
      pa[0] = (short)f2bf(s[p2 * 2][0]);     pa[1] = (short)f2bf(s[p2 * 2][1]);
      pa[2] = (short)f2bf(s[p2 * 2][2]);     pa[3] = (short)f2bf(s[p2 * 2][3]);
      pa[4] = (short)f2bf(s[p2 * 2 + 1][0]); pa[5] = (short)f2bf(s[p2 * 2 + 1][1]);
      pa[6] = (short)f2bf(s[p2 * 2 + 1][2]); pa[7] = (short)f2bf(s[p2 * 2 + 1][3]);
      const int jb0 = min(jbase + p2 * 32 + fs * 4, 2044);
      const int jb1 = min(jbase + p2 * 32 + 16 + fs * 4, 2044);
#pragma unroll
      for (int nt = 0; nt < 2; ++nt) {
        const short* vrow = vtg + (size_t)(w * 32 + nt * 16 + fr) * 2048;
        const short4 v0 = *(const short4*)(vrow + jb0);
        const short4 v1 = *(const short4*)(vrow + jb1);
        bf16x8 vf;
        vf[0] = v0.x; vf[1] = v0.y; vf[2] = v0.z; vf[3] = v0.w;
        vf[4] = v1.x; vf[5] = v1.y; vf[6] = v1.z; vf[7] = v1.w;
        oa[nt] = __builtin_amdgcn_mfma_f32_16x16x32_bf16(pa, vf, oa[nt], 0, 0, 0);
      }
    }
  }

#pragma unroll
  for (int jj = 0; jj < 4; ++jj) {
    const float lq = __shfl(l, fs * 4 + jj, 64);
    const float inv = (lq > 0.f) ? (1.f / lq) : 0.f;
    const int q = fs * 4 + jj;
    Ot[w][q][fr] = (short)f2bf(oa[0][jj] * inv);
    Ot[w][q][16 + fr] = (short)f2bf(oa[1][jj] * inv);
  }
  __syncthreads();

  // out-proj, full K=256: wave w owns col-tiles 2w, 2w+1
  f32x4 acc2[2];
  acc2[0] = (f32x4){0.f, 0.f, 0.f, 0.f};
  acc2[1] = (f32x4){0.f, 0.f, 0.f, 0.f};
#pragma unroll
  for (int ks = 0; ks < 8; ++ks) {
    const bf16x8 afrag = *(const bf16x8*)&Ot[ks][fr][fs * 8];
#pragma unroll
    for (int nt2 = 0; nt2 < 2; ++nt2) {
      const int col_row = (w * 2 + nt2) * 16 + fr;
      const bf16x8 bfrag =
          *(const bf16x8*)(out_t + (size_t)col_row * 256 + ks * 32 + fs * 8);
      acc2[nt2] = __builtin_amdgcn_mfma_f32_16x16x32_bf16(afrag, bfrag, acc2[nt2], 0, 0, 0);
    }
  }

  float d[2][4], ps[4], pq[4];
#pragma unroll
  for (int jj = 0; jj < 4; ++jj) {
    const int node = q0 + fs * 4 + jj;
    const int noder = min(node, 2047);
#pragma unroll
    for (int nt2 = 0; nt2 < 2; ++nt2) {
      const int col = w * 32 + nt2 * 16 + fr;
      d[nt2][jj] = acc2[nt2][jj] + outb[col] + h[(size_t)noder * 256 + col];
    }
    ps[jj] = d[0][jj] + d[1][jj];
    pq[jj] = d[0][jj] * d[0][jj] + d[1][jj] * d[1][jj];
#pragma unroll
    for (int m = 1; m <= 8; m <<= 1) {
      ps[jj] += __shfl_xor(ps[jj], m, 64);
      pq[jj] += __shfl_xor(pq[jj], m, 64);
    }
  }
  if (fr == 0) {
#pragma unroll
    for (int jj = 0; jj < 4; ++jj) {
      redS[w][fs * 4 + jj] = ps[jj];
      redQ[w][fs * 4 + jj] = pq[jj];
    }
  }
  __syncthreads();

#pragma unroll
  for (int jj = 0; jj < 4; ++jj) {
    const int row = fs * 4 + jj;
    float S = 0.f, Q = 0.f;
#pragma unroll
    for (int ww = 0; ww < 8; ++ww) { S += redS[ww][row]; Q += redQ[ww][row]; }
    const float mean = S * (1.f / 256.f);
    const float var = Q * (1.f / 256.f) - mean * mean;
    const float rs = rsqrtf(var + 1e-5f);
    const int node = q0 + row;
    if (active && node < je) {
#pragma unroll
      for (int nt2 = 0; nt2 < 2; ++nt2) {
        const int col = w * 32 + nt2 * 16 + fr;
        const float o = (d[nt2][jj] - mean) * rs * lns[col] + lnb[col];
        h[(size_t)node * 256 + col] = o;
        hb[(size_t)node * 256 + col] = (short)f2bf(o);
      }
    }
  }
}

// ---------------- ff1 + relu + ff2 + residual + LN2, one block per 16 rows ----------------
// 512 threads = 8 waves. Phase 1: wave w computes intermediate cols [w*128,(w+1)*128)
// at full K=256 (direct L2 fragment reads, r10-verified layout), relu+bias -> bf16 LDS
// Ff[16][1036]. Phase 2: wave w computes out cols [w*32,(w+1)*32) at full K=1024 from
// Ff, then block does residual + LN2 via LDS reduce (r15-proven epilogue). No partials.
__global__ __launch_bounds__(512) void ff_fused(
    const short* __restrict__ hb_in, const short* __restrict__ ff1_t,
    const float* __restrict__ ff1b, const short* __restrict__ ff2_t,
    const float* __restrict__ ff2b, const float* __restrict__ lns,
    const float* __restrict__ lnb, float* __restrict__ h, short* __restrict__ hb) {
  __shared__ short Ff[16][1036];
  __shared__ float redS[8][16], redQ[8][16];
  const int w = threadIdx.x >> 6;
  const int lane = threadIdx.x & 63;
  const int fr = lane & 15, fs = lane >> 4;
  const int rb = blockIdx.x * 16;

  // ---- ff1: intermediate cols for this wave ----
  const short* ap = hb_in + (size_t)(rb + fr) * 256 + fs * 8;
#pragma unroll
  for (int nt = 0; nt < 8; ++nt) {
    const int colr = w * 128 + nt * 16 + fr;  // ff1 out col (row of ff1_t)
    f32x4 acc = (f32x4){0.f, 0.f, 0.f, 0.f};
    const short* bp = ff1_t + (size_t)colr * 256 + fs * 8;
#pragma unroll
    for (int k0 = 0; k0 < 256; k0 += 32) {
      const bf16x8 af = *(const bf16x8*)(ap + k0);
      const bf16x8 bf = *(const bf16x8*)(bp + k0);
      acc = __builtin_amdgcn_mfma_f32_16x16x32_bf16(af, bf, acc, 0, 0, 0);
    }
    const float bv = ff1b[colr];
#pragma unroll
    for (int j = 0; j < 4; ++j) {
      Ff[fs * 4 + j][colr] = (short)f2bf(fmaxf(acc[j] + bv, 0.f));
    }
  }
  __syncthreads();

  // ---- ff2: out cols [w*32, w*32+32), K=1024 from Ff ----
  f32x4 acc2[2];
  acc2[0] = (f32x4){0.f, 0.f, 0.f, 0.f};
  acc2[1] = (f32x4){0.f, 0.f, 0.f, 0.f};
  for (int k0 = 0; k0 < 1024; k0 += 32) {
    const bf16x8 af = *(const bf16x8*)&Ff[fr][k0 + fs * 8];
#pragma unroll
    for (int nt2 = 0; nt2 < 2; ++nt2) {
      const int colr = w * 32 + nt2 * 16 + fr;
      const bf16x8 bf = *(const bf16x8*)(ff2_t + (size_t)colr * 1024 + k0 + fs * 8);
      acc2[nt2] = __builtin_amdgcn_mfma_f32_16x16x32_bf16(af, bf, acc2[nt2], 0, 0, 0);
    }
  }

  // ---- residual + ff2_b; LN2 via 8-wave reduce ----
  float d[2][4], ps[4], pq[4];
#pragma unroll
  for (int jj = 0; jj < 4; ++jj) {
    const int row = rb + fs * 4 + jj;
#pragma unroll
    for (int nt2 = 0; nt2 < 2; ++nt2) {
      const int col = w * 32 + nt2 * 16 + fr;
      d[nt2][jj] = acc2[nt2][jj] + ff2b[col] + h[(size_t)row * 256 + col];
    }
    ps[jj] = d[0][jj] + d[1][jj];
    pq[jj] = d[0][jj] * d[0][jj] + d[1][jj] * d[1][jj];
#pragma unroll
    for (int m = 1; m <= 8; m <<= 1) {
      ps[jj] += __shfl_xor(ps[jj], m, 64);
      pq[jj] += __shfl_xor(pq[jj], m, 64);
    }
  }
  if (fr == 0) {
#pragma unroll
    for (int jj = 0; jj < 4; ++jj) {
      redS[w][fs * 4 + jj] = ps[jj];
      redQ[w][fs * 4 + jj] = pq[jj];
    }
  }
  __syncthreads();

#pragma unroll
  for (int jj = 0; jj < 4; ++jj) {
    const int row = fs * 4 + jj;
    float S = 0.f, Q = 0.f;
#pragma unroll
    for (int ww = 0; ww < 8; ++ww) { S += redS[ww][row]; Q += redQ[ww][row]; }
    const float mean = S * (1.f / 256.f);
    const float var = Q * (1.f / 256.f) - mean * mean;
    const float rs = rsqrtf(var + 1e-5f);
    const int node = rb + row;
#pragma unroll
    for (int nt2 = 0; nt2 < 2; ++nt2) {
      const int col = w * 32 + nt2 * 16 + fr;
      const float o = (d[nt2][jj] - mean) * rs * lns[col] + lnb[col];
      h[(size_t)node * 256 + col] = o;
      hb[(size_t)node * 256 + col] = (short)f2bf(o);
    }
  }
}

// ---------------- heads: lat (blocks 0..31) + beta (blocks 32..159), one dispatch ----------------
__global__ __launch_bounds__(256) void heads_kernel(
    const short* __restrict__ A, const short* __restrict__ lat_t,
    const float* __restrict__ lat_b, float* __restrict__ lat_out,
    const short* __restrict__ b1_t, const float* __restrict__ b1b,
    const float* __restrict__ w2, const float* __restrict__ b2b,
    float* __restrict__ beta) {
  __shared__ short smem[64 * 128 * 2];
  const int t = threadIdx.x;
  const int lane = t & 63, w = t >> 6;
  const int fr = lane & 15, fs = lane >> 4;

  if (blockIdx.x < 32) {  // ---- lat tile: GEMM (N=32, K=256) + row-normalize ----
    short* As = smem;
    short* Bs = smem + 64 * 128;
    const int bm = blockIdx.x;
    const int srow = t >> 2, sq = t & 3;
    const int rx = srow & 7;
    f32x4 acc[2];
    acc[0] = (f32x4){0.f, 0.f, 0.f, 0.f};
    acc[1] = (f32x4){0.f, 0.f, 0.f, 0.f};
    const short* ap = A + (size_t)(bm * 64 + srow) * 256;
    const short* bp = lat_t + (size_t)srow * 256;
    const int ar = w * 16 + fr;
    for (int k0 = 0; k0 < 256; k0 += 128) {
      bf16x8 av[4], bv[4];
#pragma unroll
      for (int i = 0; i < 4; ++i) av[i] = *(const bf16x8*)(ap + k0 + (sq * 4 + i) * 8);
      if (srow < 32) {
#pragma unroll
        for (int i = 0; i < 4; ++i) bv[i] = *(const bf16x8*)(bp + k0 + (sq * 4 + i) * 8);
      } else {
#pragma unroll
        for (int i = 0; i < 4; ++i) bv[i] = (bf16x8){0, 0, 0, 0, 0, 0, 0, 0};
      }
      __syncthreads();
#pragma unroll
      for (int i = 0; i < 4; ++i) {
        const int s = sq * 4 + i;
        *(bf16x8*)(As + srow * 128 + ((s ^ rx) * 8)) = av[i];
        *(bf16x8*)(Bs + srow * 128 + ((s ^ rx) * 8)) = bv[i];
      }
      __syncthreads();
#pragma unroll
      for (int ks = 0; ks < 4; ++ks) {
        const int u = ks * 4 + fs;
        bf16x8 a0 = *(const bf16x8*)(As + ar * 128 + ((u ^ (ar & 7)) * 8));
        bf16x8 b0 = *(const bf16x8*)(Bs + fr * 128 + ((u ^ (fr & 7)) * 8));
        bf16x8 b1 = *(const bf16x8*)(Bs + (16 + fr) * 128 + ((u ^ ((16 + fr) & 7)) * 8));
        acc[0] = __builtin_amdgcn_mfma_f32_16x16x32_bf16(a0, b0, acc[0], 0, 0, 0);
        acc[1] = __builtin_amdgcn_mfma_f32_16x16x32_bf16(a0, b1, acc[1], 0, 0, 0);
      }
    }
    const float b0v = lat_b[fr], b1v = lat_b[16 + fr];
#pragma unroll
    for (int j = 0; j < 4; ++j) {
      const int row = bm * 64 + w * 16 + fs * 4 + j;
      float v0 = acc[0][j] + b0v;
      float v1 = acc[1][j] + b1v;
      float ss = v0 * v0 + v1 * v1;
      ss += __shfl_xor(ss, 1, 64);
      ss += __shfl_xor(ss, 2, 64);
      ss += __shfl_xor(ss, 4, 64);
      ss += __shfl_xor(ss, 8, 64);
      const float inv = 5.656854249492381f / fmaxf(sqrtf(ss), 1e-12f);
      lat_out[(size_t)row * 32 + fr] = v0 * inv;
      lat_out[(size_t)row * 32 + 16 + fr] = v1 * inv;
    }
  } else {  // ---- beta: sigmoid(relu(h@W1+b1)@w2+b2), 16 rows per block ----
    float* red = (float*)smem;
    const int rb = (blockIdx.x - 32) * 16;
    f32x4 acc[2];
    acc[0] = (f32x4){0.f, 0.f, 0.f, 0.f};
    acc[1] = (f32x4){0.f, 0.f, 0.f, 0.f};
    const short* ap = A + (size_t)(rb + fr) * 256;
    const short* bp = b1_t + (size_t)(w * 32 + fr) * 256;
    for (int k0 = 0; k0 < 256; k0 += 32) {
      const bf16x8 af = *(const bf16x8*)(ap + k0 + fs * 8);
#pragma unroll
      for (int n = 0; n < 2; ++n) {
        const bf16x8 bf = *(const bf16x8*)(bp + (size_t)n * 16 * 256 + k0 + fs * 8);
        acc[n] = __builtin_amdgcn_mfma_f32_16x16x32_bf16(af, bf, acc[n], 0, 0, 0);
      }
    }
    const int c0 = w * 32 + fr, c1 = c0 + 16;
    const float b0 = b1b[c0], b1 = b1b[c1];
    const float w0 = w2[c0], w1 = w2[c1];
    float part[4];
#pragma unroll
    for (int j = 0; j < 4; ++j) {
      const float d0 = fmaxf(acc[0][j] + b0, 0.f);
      const float d1 = fmaxf(acc[1][j] + b1, 0.f);
      part[j] = d0 * w0 + d1 * w1;
#pragma unroll
      for (int m = 1; m <= 8; m <<= 1) part[j] += __shfl_xor(part[j], m, 64);
    }
    if (fr == 0) {
#pragma unroll
      for (int j = 0; j < 4; ++j) red[w * 16 + fs * 4 + j] = part[j];
    }
    __syncthreads();
    if (t < 16) {
      const float S = red[t] + red[16 + t] + red[32 + t] + red[48 + t] + b2b[0];
      float sgm = 1.f / (1.f + __expf(-S));
      sgm = fminf(fmaxf(sgm, 1e-6f), 1.f - 1e-6f);
      beta[rb + t] = sgm;
    }
  }
}

// ---------------- launch ----------------
extern "C" void kernel_launch(void* const* d_in, const int* in_sizes, int n_in,
                              void* d_out, int out_size, void* d_ws, size_t ws_size,
                              hipStream_t stream) {
  const int N = 2048, D = 256, FF = 1024, L = 4;

  const float* x     = (const float*)d_in[0];
  const int*   batch = (const int*)d_in[2];
  const float* Wi    = (const float*)d_in[3];
  const float* bi    = (const float*)d_in[4];
  const float* qkv_w = (const float*)d_in[5];
  const float* qkv_b = (const float*)d_in[6];
  const float* out_w = (const float*)d_in[7];
  const float* out_b = (const float*)d_in[8];
  const float* ff1_w = (const float*)d_in[9];
  const float* ff1_b = (const float*)d_in[10];
  const float* ff2_w = (const float*)d_in[11];
  const float* ff2_b = (const float*)d_in[12];
  const float* ln1_s = (const float*)d_in[13];
  const float* ln1_b = (const float*)d_in[14];
  const float* ln2_s = (const float*)d_in[15];
  const float* ln2_b = (const float*)d_in[16];
  const float* lat_w = (const float*)d_in[17];
  const float* lat_b = (const float*)d_in[18];
  const float* b1_w  = (const float*)d_in[19];
  const float* b1_b  = (const float*)d_in[20];
  const float* b2_w  = (const float*)d_in[21];
  const float* b2_b  = (const float*)d_in[22];

  float* ws = (float*)d_ws;
  float* h      = ws;                              // N*D f32
  int*  starts  = (int*)(h + (size_t)N * D);       // 32 ints
  int*  meta    = starts + 32;                     // 448 ints
  short* hb     = (short*)(meta + 448);            // N*D bf16
  short* qkvb   = hb + (size_t)N * D;              // N*3D bf16 (V cols unused)
  short* vtg    = qkvb + (size_t)N * 3 * D;        // 256*2048 bf16 (V^T per layer)
  short* qkv_t  = vtg + (size_t)256 * 2048;
  short* out_t  = qkv_t + (size_t)L * 768 * 256;
  short* ff1_t  = out_t + (size_t)L * 256 * 256;
  short* ff2_t  = ff1_t + (size_t)L * 1024 * 256;
  short* b1_t   = ff2_t + (size_t)L * 256 * 1024;
  short* lat_t  = b1_t + (size_t)128 * 256;

  float* beta_out = (float*)d_out;
  float* lat_out  = beta_out + N;

  pack_inproj<<<3113 + 2048, 256, 0, stream>>>(
      qkv_w, out_w, ff1_w, ff2_w, b1_w, lat_w,
      qkv_t, out_t, ff1_t, ff2_t, b1_t, lat_t,
      batch, starts, meta, x, Wi, bi, h, hb);

  for (int l = 0; l < L; ++l) {
    // qkv = h @ qkv_w + b -> bf16 Q,K (+ coalesced V^T)
    gemm_qkv<<<dim3(12, 32), 256, 0, stream>>>(
        hb, qkv_t + (size_t)l * 768 * 256, qkv_b + (size_t)l * 768,
        qkvb, vtg, 768, 256);
    // attention + out-proj + residual + LN1
    attn_fused<<<144, 512, 0, stream>>>(
        qkvb, vtg, meta, out_t + (size_t)l * 256 * 256, out_b + (size_t)l * 256,
        ln1_s + (size_t)l * D, ln1_b + (size_t)l * D, h, hb);
    // ff1 + relu + ff2 + residual + LN2
    ff_fused<<<128, 512, 0, stream>>>(
        hb, ff1_t + (size_t)l * FF * 256, ff1_b + (size_t)l * FF,
        ff2_t + (size_t)l * 256 * FF, ff2_b + (size_t)l * 256,
        ln2_s + (size_t)l * D, ln2_b + (size_t)l * D, h, hb);
  }

  heads_kernel<<<160, 256, 0, stream>>>(hb, lat_t, lat_b, lat_out,
                                        b1_t, b1_b, b2_w, b2_b, beta_out);
}

// Round 17
// 227.038 us; speedup vs baseline: 1.2546x; 1.2546x over previous
//
#include <hip/hip_runtime.h>
#include <hip/hip_bf16.h>

typedef __attribute__((ext_vector_type(8))) short bf16x8;
typedef __attribute__((ext_vector_type(4))) float f32x4;

// ---------------- helpers ----------------
__device__ inline float wave_sum64(float v) {
#pragma unroll
  for (int m = 32; m >= 1; m >>= 1) v += __shfl_xor(v, m, 64);
  return v;
}
__device__ inline ushort f2bf(float f) {  // RNE float->bf16
  uint u = __float_as_uint(f);
  return (ushort)((u + 0x7FFFu + ((u >> 16) & 1u)) >> 16);
}

// ---------------- weight pack + starts/meta + input projection (one dispatch) ----------------
__global__ __launch_bounds__(256) void pack_inproj(
    const float* __restrict__ qkv_w, const float* __restrict__ out_w,
    const float* __restrict__ ff1_w, const float* __restrict__ ff2_w,
    const float* __restrict__ b1_w, const float* __restrict__ lat_w,
    short* __restrict__ qkv_t, short* __restrict__ out_t,
    short* __restrict__ ff1_t, short* __restrict__ ff2_t,
    short* __restrict__ b1_t, short* __restrict__ lat_t,
    const int* __restrict__ batch, int* __restrict__ starts, int* __restrict__ meta,
    const float* __restrict__ x, const float* __restrict__ Wi,
    const float* __restrict__ bi, float* __restrict__ h, short* __restrict__ hb) {
  int t = blockIdx.x;
  __shared__ float tile[32][33];

  if (t >= 3113) {  // input projection: one row per block
    const int row = t - 3113;
    const int j = threadIdx.x;
    float* xs = &tile[0][0];
    if (j < 16) xs[j] = x[(size_t)row * 16 + j];
    __syncthreads();
    float acc = bi[j];
#pragma unroll
    for (int k = 0; k < 16; ++k) acc += xs[k] * Wi[k * 256 + j];
    h[(size_t)row * 256 + j] = acc;
    hb[(size_t)row * 256 + j] = (short)f2bf(acc);
    return;
  }
  if (t == 3112) {  // graph boundaries + graph-aligned 16-row tile list
    for (int i = threadIdx.x; i < 2048; i += 256) {
      int b = batch[i];
      if (i == 0) {
        for (int g = 0; g <= b; ++g) starts[g] = 0;
      } else {
        int bp = batch[i - 1];
        for (int g = bp + 1; g <= b; ++g) starts[g] = i;
      }
      if (i == 2047) {
        for (int g = b + 1; g <= 16; ++g) starts[g] = 2048;
      }
    }
    __syncthreads();
    if (threadIdx.x == 0) {
      int nt = 0;
      for (int g = 0; g < 16; ++g) {
        const int js = starts[g], je = starts[g + 1];
        for (int q0 = js; q0 < je; q0 += 16) {
          meta[1 + nt * 3] = q0;
          meta[2 + nt * 3] = js;
          meta[3 + nt * 3] = je;
          ++nt;
        }
      }
      meta[0] = nt;
    }
    return;
  }
  const float* src;
  short* dst;
  int Kd, Nd, rem;
  if (t < 768) {
    int l = t / 192; rem = t % 192; Kd = 256; Nd = 768;
    src = qkv_w + (size_t)l * Kd * Nd; dst = qkv_t + (size_t)l * Nd * Kd;
  } else if (t < 1024) {
    t -= 768; int l = t / 64; rem = t % 64; Kd = 256; Nd = 256;
    src = out_w + (size_t)l * Kd * Nd; dst = out_t + (size_t)l * Nd * Kd;
  } else if (t < 2048) {
    t -= 1024; int l = t / 256; rem = t % 256; Kd = 256; Nd = 1024;
    src = ff1_w + (size_t)l * Kd * Nd; dst = ff1_t + (size_t)l * Nd * Kd;
  } else if (t < 3072) {
    t -= 2048; int l = t / 256; rem = t % 256; Kd = 1024; Nd = 256;
    src = ff2_w + (size_t)l * Kd * Nd; dst = ff2_t + (size_t)l * Nd * Kd;
  } else if (t < 3104) {
    rem = t - 3072; Kd = 256; Nd = 128; src = b1_w; dst = b1_t;
  } else {
    rem = t - 3104; Kd = 256; Nd = 32; src = lat_w; dst = lat_t;
  }
  const int ntn = Nd / 32;
  const int kt = rem / ntn, nt = rem % ntn;
  const int tx = threadIdx.x & 31, ty = threadIdx.x >> 5;
#pragma unroll
  for (int r = 0; r < 4; ++r) {
    int k = kt * 32 + ty + r * 8;
    tile[ty + r * 8][tx] = src[(size_t)k * Nd + nt * 32 + tx];
  }
  __syncthreads();
#pragma unroll
  for (int r = 0; r < 4; ++r) {
    int n = nt * 32 + ty + r * 8;
    dst[(size_t)n * Kd + kt * 32 + tx] = (short)f2bf(tile[tx][ty + r * 8]);
  }
}

// ---------------- MFMA bf16 GEMM for qkv (r11-proven): bf16 Q,K + coalesced V^T ----------------
__global__ __launch_bounds__(256) void gemm_qkv(
    const short* __restrict__ A, const short* __restrict__ Bt,
    const float* __restrict__ bias, short* __restrict__ Cb,
    short* __restrict__ vtg, int N, int K) {
  __shared__ short As[64 * 128];
  __shared__ short Bs[64 * 128];

  const int t = threadIdx.x;
  const int bm = blockIdx.y, bn = blockIdx.x;
  const int srow = t >> 2, sq = t & 3;
  const int lane = t & 63, wid = t >> 6;
  const int wr = wid >> 1, wc = wid & 1;
  const int fr = lane & 15, fs = lane >> 4;
  const int rx = srow & 7;

  f32x4 acc[2][2];
#pragma unroll
  for (int m = 0; m < 2; ++m)
#pragma unroll
    for (int n = 0; n < 2; ++n) acc[m][n] = (f32x4){0.f, 0.f, 0.f, 0.f};

  const short* ap = A + (size_t)(bm * 64 + srow) * K;
  const int ng = bn * 64 + srow;
  const short* bp = Bt + (size_t)ng * K;
  const int ar0 = wr * 32 + fr, ar1 = ar0 + 16;
  const int bc0 = wc * 32 + fr, bc1 = bc0 + 16;

  for (int k0 = 0; k0 < K; k0 += 128) {
    bf16x8 av[4], bv[4];
#pragma unroll
    for (int i = 0; i < 4; ++i) av[i] = *(const bf16x8*)(ap + k0 + (sq * 4 + i) * 8);
#pragma unroll
    for (int i = 0; i < 4; ++i) bv[i] = *(const bf16x8*)(bp + k0 + (sq * 4 + i) * 8);
    __syncthreads();
#pragma unroll
    for (int i = 0; i < 4; ++i) {
      const int s = sq * 4 + i;
      *(bf16x8*)(As + srow * 128 + ((s ^ rx) * 8)) = av[i];
      *(bf16x8*)(Bs + srow * 128 + ((s ^ rx) * 8)) = bv[i];
    }
    __syncthreads();
#pragma unroll
    for (int ks = 0; ks < 4; ++ks) {
      const int u = ks * 4 + fs;
      bf16x8 a0 = *(const bf16x8*)(As + ar0 * 128 + ((u ^ (ar0 & 7)) * 8));
      bf16x8 a1 = *(const bf16x8*)(As + ar1 * 128 + ((u ^ (ar1 & 7)) * 8));
      bf16x8 b0 = *(const bf16x8*)(Bs + bc0 * 128 + ((u ^ (bc0 & 7)) * 8));
      bf16x8 b1 = *(const bf16x8*)(Bs + bc1 * 128 + ((u ^ (bc1 & 7)) * 8));
      acc[0][0] = __builtin_amdgcn_mfma_f32_16x16x32_bf16(a0, b0, acc[0][0], 0, 0, 0);
      acc[0][1] = __builtin_amdgcn_mfma_f32_16x16x32_bf16(a0, b1, acc[0][1], 0, 0, 0);
      acc[1][0] = __builtin_amdgcn_mfma_f32_16x16x32_bf16(a1, b0, acc[1][0], 0, 0, 0);
      acc[1][1] = __builtin_amdgcn_mfma_f32_16x16x32_bf16(a1, b1, acc[1][1], 0, 0, 0);
    }
  }

  if (bn < 8) {  // Q,K columns -> bf16
#pragma unroll
    for (int n = 0; n < 2; ++n) {
      const int col = bn * 64 + wc * 32 + n * 16 + fr;
      const float bvv = bias[col];
#pragma unroll
      for (int m = 0; m < 2; ++m) {
        const int rbase = bm * 64 + wr * 32 + m * 16 + fs * 4;
#pragma unroll
        for (int j = 0; j < 4; ++j) {
          Cb[(size_t)(rbase + j) * N + col] = (short)f2bf(acc[m][n][j] + bvv);
        }
      }
    }
  } else {  // V columns -> coalesced V^T
    short* tr = As;  // reuse LDS: [64 cols][68 rows]
    __syncthreads();
#pragma unroll
    for (int n = 0; n < 2; ++n) {
      const int c = wc * 32 + n * 16 + fr;
      const float bvv = bias[bn * 64 + c];
#pragma unroll
      for (int m = 0; m < 2; ++m)
#pragma unroll
        for (int j = 0; j < 4; ++j) {
          const int r = wr * 32 + m * 16 + fs * 4 + j;
          tr[c * 68 + r] = (short)f2bf(acc[m][n][j] + bvv);
        }
    }
    __syncthreads();
    const int tx = t & 63, ty = t >> 6;
    const int d0 = bn * 64 - 512, rb = bm * 64;
#pragma unroll
    for (int r = 0; r < 16; ++r) {
      const int d = ty * 16 + r;
      vtg[(size_t)(d0 + d) * 2048 + rb + tx] = tr[d * 68 + tx];
    }
  }
}

// ---------------- attention + full out-proj + residual + LN1 (r15-proven winner) ----------------
__global__ __launch_bounds__(512) void attn_fused(
    const short* __restrict__ qkv, const short* __restrict__ vtg,
    const int* __restrict__ meta, const short* __restrict__ out_t,
    const float* __restrict__ outb, const float* __restrict__ lns,
    const float* __restrict__ lnb, float* __restrict__ h, short* __restrict__ hb) {
  __shared__ short Ot[8][16][40];
  __shared__ float redS[8][16], redQ[8][16];
  const int w = threadIdx.x >> 6;  // wave = head
  const int tile = blockIdx.x;
  const bool active = (tile < meta[0]);
  const int lane = threadIdx.x & 63;
  const int fr = lane & 15, fs = lane >> 4;
  const int q0 = active ? meta[1 + tile * 3] : 0;
  const int js = active ? meta[2 + tile * 3] : 0;
  const int je = active ? meta[3 + tile * 3] : 0;
  const int jbase = js & ~15;
  const int njt = active ? ((je - jbase + 15) >> 4) : 0;  // <=16
  const float scale = 0.17677669529663687f;  // 1/sqrt(32)

  const int qrow = min(q0 + fr, 2047);
  const bf16x8 qf = *(const bf16x8*)(qkv + (size_t)qrow * 768 + w * 32 + fs * 8);
  const int jeq = (q0 + fr < je) ? je : 0;

  f32x4 s[16];
#pragma unroll
  for (int jt = 0; jt < 16; ++jt)
    s[jt] = (f32x4){-3.0e38f, -3.0e38f, -3.0e38f, -3.0e38f};

#pragma unroll
  for (int jt = 0; jt < 16; ++jt) {
    if (jt < njt) {
      const int krow = min(jbase + jt * 16 + fr, 2047);
      const bf16x8 kf = *(const bf16x8*)(qkv + (size_t)krow * 768 + 256 + w * 32 + fs * 8);
      s[jt] = __builtin_amdgcn_mfma_f32_16x16x32_bf16(
          kf, qf, (f32x4){0.f, 0.f, 0.f, 0.f}, 0, 0, 0);
    }
  }
  float mx = -3.0e38f;
#pragma unroll
  for (int jt = 0; jt < 16; ++jt) {
    if (jt < njt) {
#pragma unroll
      for (int jj = 0; jj < 4; ++jj) {
        const int j = jbase + jt * 16 + fs * 4 + jj;
        const bool valid = (j >= js) && (j < jeq);
        s[jt][jj] = valid ? s[jt][jj] * scale : -3.0e38f;
        mx = fmaxf(mx, s[jt][jj]);
      }
    }
  }
  mx = fmaxf(mx, __shfl_xor(mx, 16, 64));
  mx = fmaxf(mx, __shfl_xor(mx, 32, 64));
  float l = 0.f;
#pragma unroll
  for (int jt = 0; jt < 16; ++jt) {
#pragma unroll
    for (int jj = 0; jj < 4; ++jj) {
      const float p = __expf(s[jt][jj] - mx);
      s[jt][jj] = p;
      l += p;
    }
  }
  l += __shfl_xor(l, 16, 64);
  l += __shfl_xor(l, 32, 64);

  f32x4 oa[2];
  oa[0] = (f32x4){0.f, 0.f, 0.f, 0.f};
  oa[1] = (f32x4){0.f, 0.f, 0.f, 0.f};
#pragma unroll
  for (int p2 = 0; p2 < 8; ++p2) {
    if (p2 * 2 < njt) {
      bf16x8 pa;
      pa[0] = (short)f2bf(s[p2 * 2][0]);     pa[1] = (short)f2bf(s[p2 * 2][1]);
      pa[2] = (short)f2bf(s[p2 * 2][2]);     pa[3] = (short)f2bf(s[p2 * 2][3]);
      pa[4] = (short)f2bf(s[p2 * 2 + 1][0]); pa[5] = (short)f2bf(s[p2 * 2 + 1][1]);
      pa[6] = (short)f2bf(s[p2 * 2 + 1][2]); pa[7] = (short)f2bf(s[p2 * 2 + 1][3]);
      const int jb0 = min(jbase + p2 * 32 + fs * 4, 2044);
      const int jb1 = min(jbase + p2 * 32 + 16 + fs * 4, 2044);
#pragma unroll
      for (int nt = 0; nt < 2; ++nt) {
        const short* vrow = vtg + (size_t)(w * 32 + nt * 16 + fr) * 2048;
        const short4 v0 = *(const short4*)(vrow + jb0);
        const short4 v1 = *(const short4*)(vrow + jb1);
        bf16x8 vf;
        vf[0] = v0.x; vf[1] = v0.y; vf[2] = v0.z; vf[3] = v0.w;
        vf[4] = v1.x; vf[5] = v1.y; vf[6] = v1.z; vf[7] = v1.w;
        oa[nt] = __builtin_amdgcn_mfma_f32_16x16x32_bf16(pa, vf, oa[nt], 0, 0, 0);
      }
    }
  }

#pragma unroll
  for (int jj = 0; jj < 4; ++jj) {
    const float lq = __shfl(l, fs * 4 + jj, 64);
    const float inv = (lq > 0.f) ? (1.f / lq) : 0.f;
    const int q = fs * 4 + jj;
    Ot[w][q][fr] = (short)f2bf(oa[0][jj] * inv);
    Ot[w][q][16 + fr] = (short)f2bf(oa[1][jj] * inv);
  }
  __syncthreads();

  // out-proj, full K=256: wave w owns col-tiles 2w, 2w+1
  f32x4 acc2[2];
  acc2[0] = (f32x4){0.f, 0.f, 0.f, 0.f};
  acc2[1] = (f32x4){0.f, 0.f, 0.f, 0.f};
#pragma unroll
  for (int ks = 0; ks < 8; ++ks) {
    const bf16x8 afrag = *(const bf16x8*)&Ot[ks][fr][fs * 8];
#pragma unroll
    for (int nt2 = 0; nt2 < 2; ++nt2) {
      const int col_row = (w * 2 + nt2) * 16 + fr;
      const bf16x8 bfrag =
          *(const bf16x8*)(out_t + (size_t)col_row * 256 + ks * 32 + fs * 8);
      acc2[nt2] = __builtin_amdgcn_mfma_f32_16x16x32_bf16(afrag, bfrag, acc2[nt2], 0, 0, 0);
    }
  }

  float d[2][4], ps[4], pq[4];
#pragma unroll
  for (int jj = 0; jj < 4; ++jj) {
    const int node = q0 + fs * 4 + jj;
    const int noder = min(node, 2047);
#pragma unroll
    for (int nt2 = 0; nt2 < 2; ++nt2) {
      const int col = w * 32 + nt2 * 16 + fr;
      d[nt2][jj] = acc2[nt2][jj] + outb[col] + h[(size_t)noder * 256 + col];
    }
    ps[jj] = d[0][jj] + d[1][jj];
    pq[jj] = d[0][jj] * d[0][jj] + d[1][jj] * d[1][jj];
#pragma unroll
    for (int m = 1; m <= 8; m <<= 1) {
      ps[jj] += __shfl_xor(ps[jj], m, 64);
      pq[jj] += __shfl_xor(pq[jj], m, 64);
    }
  }
  if (fr == 0) {
#pragma unroll
    for (int jj = 0; jj < 4; ++jj) {
      redS[w][fs * 4 + jj] = ps[jj];
      redQ[w][fs * 4 + jj] = pq[jj];
    }
  }
  __syncthreads();

#pragma unroll
  for (int jj = 0; jj < 4; ++jj) {
    const int row = fs * 4 + jj;
    float S = 0.f, Q = 0.f;
#pragma unroll
    for (int ww = 0; ww < 8; ++ww) { S += redS[ww][row]; Q += redQ[ww][row]; }
    const float mean = S * (1.f / 256.f);
    const float var = Q * (1.f / 256.f) - mean * mean;
    const float rs = rsqrtf(var + 1e-5f);
    const int node = q0 + row;
    if (active && node < je) {
#pragma unroll
      for (int nt2 = 0; nt2 < 2; ++nt2) {
        const int col = w * 32 + nt2 * 16 + fr;
        const float o = (d[nt2][jj] - mean) * rs * lns[col] + lnb[col];
        h[(size_t)node * 256 + col] = o;
        hb[(size_t)node * 256 + col] = (short)f2bf(o);
      }
    }
  }
}

// ---------------- ff half: ff1 (full K=256) for one intermediate half + ff2 over that
// K-half -> f32 partial. Grid (128 row-tiles, 2 halves) x 512 thr = 2 waves/SIMD.
// No ffb round-trip, no cross-block sync; ln_kernel<2> finishes residual+LN2.
__global__ __launch_bounds__(512) void ff_semi(
    const short* __restrict__ hb_in, const short* __restrict__ ff1_t,
    const float* __restrict__ ff1b, const short* __restrict__ ff2_t,
    const float* __restrict__ ff2b, float* __restrict__ tmp) {
  __shared__ short Ff[16][520];  // 512 cols + pad (stride 1040B -> 2-way banked, free)
  const int w = threadIdx.x >> 6;
  const int lane = threadIdx.x & 63;
  const int fr = lane & 15, fs = lane >> 4;
  const int rb = blockIdx.x * 16;
  const int z = blockIdx.y;       // K-half
  const int cbase = z * 512;      // intermediate col base

  // ---- ff1: this half's intermediate cols; wave w owns cols cbase+w*64..+64 ----
  const short* ap = hb_in + (size_t)(rb + fr) * 256 + fs * 8;
#pragma unroll
  for (int nt = 0; nt < 4; ++nt) {
    const int colr = cbase + w * 64 + nt * 16 + fr;  // ff1 out col (row of ff1_t)
    f32x4 acc = (f32x4){0.f, 0.f, 0.f, 0.f};
    const short* bp = ff1_t + (size_t)colr * 256 + fs * 8;
#pragma unroll
    for (int k0 = 0; k0 < 256; k0 += 32) {
      const bf16x8 af = *(const bf16x8*)(ap + k0);
      const bf16x8 bf = *(const bf16x8*)(bp + k0);
      acc = __builtin_amdgcn_mfma_f32_16x16x32_bf16(af, bf, acc, 0, 0, 0);
    }
    const float bv = ff1b[colr];
    const int lc = w * 64 + nt * 16 + fr;  // local col in Ff
#pragma unroll
    for (int j = 0; j < 4; ++j) {
      Ff[fs * 4 + j][lc] = (short)f2bf(fmaxf(acc[j] + bv, 0.f));
    }
  }
  __syncthreads();

  // ---- ff2 over this K-half: wave w owns out cols [w*32, w*32+32) ----
  f32x4 acc2[2];
  acc2[0] = (f32x4){0.f, 0.f, 0.f, 0.f};
  acc2[1] = (f32x4){0.f, 0.f, 0.f, 0.f};
  for (int k0 = 0; k0 < 512; k0 += 32) {
    const bf16x8 af = *(const bf16x8*)&Ff[fr][k0 + fs * 8];
#pragma unroll
    for (int nt2 = 0; nt2 < 2; ++nt2) {
      const int colr = w * 32 + nt2 * 16 + fr;
      const bf16x8 bf =
          *(const bf16x8*)(ff2_t + (size_t)colr * 1024 + cbase + k0 + fs * 8);
      acc2[nt2] = __builtin_amdgcn_mfma_f32_16x16x32_bf16(af, bf, acc2[nt2], 0, 0, 0);
    }
  }

  // ---- f32 partial store (bias added by z==0) ----
#pragma unroll
  for (int jj = 0; jj < 4; ++jj) {
    const int row = rb + fs * 4 + jj;
#pragma unroll
    for (int nt2 = 0; nt2 < 2; ++nt2) {
      const int col = w * 32 + nt2 * 16 + fr;
      const float bvv = (z == 0) ? ff2b[col] : 0.f;
      tmp[((size_t)z * 2048 + row) * 256 + col] = acc2[nt2][jj] + bvv;
    }
  }
}

// ---------------- fused residual + P-partial sum + LayerNorm; writes f32 + bf16 ----------------
template <int P>
__global__ __launch_bounds__(256) void ln_kernel(
    const float* __restrict__ base, const float* __restrict__ delta,
    const float* __restrict__ s, const float* __restrict__ b,
    float* __restrict__ outf, short* __restrict__ outb) {
  const int row = blockIdx.x * 4 + (threadIdx.x >> 6);
  const int lane = threadIdx.x & 63;
  float4 v = *(const float4*)(base + (size_t)row * 256 + lane * 4);
#pragma unroll
  for (int p = 0; p < P; ++p) {
    const float4 xb = *(const float4*)(delta + (size_t)(p * 2048 + row) * 256 + lane * 4);
    v.x += xb.x; v.y += xb.y; v.z += xb.z; v.w += xb.w;
  }
  float sum = wave_sum64(v.x + v.y + v.z + v.w);
  const float mean = sum * (1.f / 256.f);
  float4 d = make_float4(v.x - mean, v.y - mean, v.z - mean, v.w - mean);
  float sq = wave_sum64(d.x * d.x + d.y * d.y + d.z * d.z + d.w * d.w);
  const float rs = rsqrtf(sq * (1.f / 256.f) + 1e-5f);
  const float4 sv = *(const float4*)(s + lane * 4);
  const float4 bv = *(const float4*)(b + lane * 4);
  float4 o = make_float4(d.x * rs * sv.x + bv.x, d.y * rs * sv.y + bv.y,
                         d.z * rs * sv.z + bv.z, d.w * rs * sv.w + bv.w);
  *(float4*)(outf + (size_t)row * 256 + lane * 4) = o;
  short4 ob;
  ob.x = (short)f2bf(o.x); ob.y = (short)f2bf(o.y);
  ob.z = (short)f2bf(o.z); ob.w = (short)f2bf(o.w);
  *(short4*)(outb + (size_t)row * 256 + lane * 4) = ob;
}

// ---------------- heads: lat (blocks 0..31) + beta (blocks 32..159), one dispatch ----------------
__global__ __launch_bounds__(256) void heads_kernel(
    const short* __restrict__ A, const short* __restrict__ lat_t,
    const float* __restrict__ lat_b, float* __restrict__ lat_out,
    const short* __restrict__ b1_t, const float* __restrict__ b1b,
    const float* __restrict__ w2, const float* __restrict__ b2b,
    float* __restrict__ beta) {
  __shared__ short smem[64 * 128 * 2];
  const int t = threadIdx.x;
  const int lane = t & 63, w = t >> 6;
  const int fr = lane & 15, fs = lane >> 4;

  if (blockIdx.x < 32) {  // ---- lat tile: GEMM (N=32, K=256) + row-normalize ----
    short* As = smem;
    short* Bs = smem + 64 * 128;
    const int bm = blockIdx.x;
    const int srow = t >> 2, sq = t & 3;
    const int rx = srow & 7;
    f32x4 acc[2];
    acc[0] = (f32x4){0.f, 0.f, 0.f, 0.f};
    acc[1] = (f32x4){0.f, 0.f, 0.f, 0.f};
    const short* ap = A + (size_t)(bm * 64 + srow) * 256;
    const short* bp = lat_t + (size_t)srow * 256;
    const int ar = w * 16 + fr;
    for (int k0 = 0; k0 < 256; k0 += 128) {
      bf16x8 av[4], bv[4];
#pragma unroll
      for (int i = 0; i < 4; ++i) av[i] = *(const bf16x8*)(ap + k0 + (sq * 4 + i) * 8);
      if (srow < 32) {
#pragma unroll
        for (int i = 0; i < 4; ++i) bv[i] = *(const bf16x8*)(bp + k0 + (sq * 4 + i) * 8);
      } else {
#pragma unroll
        for (int i = 0; i < 4; ++i) bv[i] = (bf16x8){0, 0, 0, 0, 0, 0, 0, 0};
      }
      __syncthreads();
#pragma unroll
      for (int i = 0; i < 4; ++i) {
        const int s = sq * 4 + i;
        *(bf16x8*)(As + srow * 128 + ((s ^ rx) * 8)) = av[i];
        *(bf16x8*)(Bs + srow * 128 + ((s ^ rx) * 8)) = bv[i];
      }
      __syncthreads();
#pragma unroll
      for (int ks = 0; ks < 4; ++ks) {
        const int u = ks * 4 + fs;
        bf16x8 a0 = *(const bf16x8*)(As + ar * 128 + ((u ^ (ar & 7)) * 8));
        bf16x8 b0 = *(const bf16x8*)(Bs + fr * 128 + ((u ^ (fr & 7)) * 8));
        bf16x8 b1 = *(const bf16x8*)(Bs + (16 + fr) * 128 + ((u ^ ((16 + fr) & 7)) * 8));
        acc[0] = __builtin_amdgcn_mfma_f32_16x16x32_bf16(a0, b0, acc[0], 0, 0, 0);
        acc[1] = __builtin_amdgcn_mfma_f32_16x16x32_bf16(a0, b1, acc[1], 0, 0, 0);
      }
    }
    const float b0v = lat_b[fr], b1v = lat_b[16 + fr];
#pragma unroll
    for (int j = 0; j < 4; ++j) {
      const int row = bm * 64 + w * 16 + fs * 4 + j;
      float v0 = acc[0][j] + b0v;
      float v1 = acc[1][j] + b1v;
      float ss = v0 * v0 + v1 * v1;
      ss += __shfl_xor(ss, 1, 64);
      ss += __shfl_xor(ss, 2, 64);
      ss += __shfl_xor(ss, 4, 64);
      ss += __shfl_xor(ss, 8, 64);
      const float inv = 5.656854249492381f / fmaxf(sqrtf(ss), 1e-12f);
      lat_out[(size_t)row * 32 + fr] = v0 * inv;
      lat_out[(size_t)row * 32 + 16 + fr] = v1 * inv;
    }
  } else {  // ---- beta: sigmoid(relu(h@W1+b1)@w2+b2), 16 rows per block ----
    float* red = (float*)smem;
    const int rb = (blockIdx.x - 32) * 16;
    f32x4 acc[2];
    acc[0] = (f32x4){0.f, 0.f, 0.f, 0.f};
    acc[1] = (f32x4){0.f, 0.f, 0.f, 0.f};
    const short* ap = A + (size_t)(rb + fr) * 256;
    const short* bp = b1_t + (size_t)(w * 32 + fr) * 256;
    for (int k0 = 0; k0 < 256; k0 += 32) {
      const bf16x8 af = *(const bf16x8*)(ap + k0 + fs * 8);
#pragma unroll
      for (int n = 0; n < 2; ++n) {
        const bf16x8 bf = *(const bf16x8*)(bp + (size_t)n * 16 * 256 + k0 + fs * 8);
        acc[n] = __builtin_amdgcn_mfma_f32_16x16x32_bf16(af, bf, acc[n], 0, 0, 0);
      }
    }
    const int c0 = w * 32 + fr, c1 = c0 + 16;
    const float b0 = b1b[c0], b1 = b1b[c1];
    const float w0 = w2[c0], w1 = w2[c1];
    float part[4];
#pragma unroll
    for (int j = 0; j < 4; ++j) {
      const float d0 = fmaxf(acc[0][j] + b0, 0.f);
      const float d1 = fmaxf(acc[1][j] + b1, 0.f);
      part[j] = d0 * w0 + d1 * w1;
#pragma unroll
      for (int m = 1; m <= 8; m <<= 1) part[j] += __shfl_xor(part[j], m, 64);
    }
    if (fr == 0) {
#pragma unroll
      for (int j = 0; j < 4; ++j) red[w * 16 + fs * 4 + j] = part[j];
    }
    __syncthreads();
    if (t < 16) {
      const float S = red[t] + red[16 + t] + red[32 + t] + red[48 + t] + b2b[0];
      float sgm = 1.f / (1.f + __expf(-S));
      sgm = fminf(fmaxf(sgm, 1e-6f), 1.f - 1e-6f);
      beta[rb + t] = sgm;
    }
  }
}

// ---------------- launch ----------------
extern "C" void kernel_launch(void* const* d_in, const int* in_sizes, int n_in,
                              void* d_out, int out_size, void* d_ws, size_t ws_size,
                              hipStream_t stream) {
  const int N = 2048, D = 256, FF = 1024, L = 4;

  const float* x     = (const float*)d_in[0];
  const int*   batch = (const int*)d_in[2];
  const float* Wi    = (const float*)d_in[3];
  const float* bi    = (const float*)d_in[4];
  const float* qkv_w = (const float*)d_in[5];
  const float* qkv_b = (const float*)d_in[6];
  const float* out_w = (const float*)d_in[7];
  const float* out_b = (const float*)d_in[8];
  const float* ff1_w = (const float*)d_in[9];
  const float* ff1_b = (const float*)d_in[10];
  const float* ff2_w = (const float*)d_in[11];
  const float* ff2_b = (const float*)d_in[12];
  const float* ln1_s = (const float*)d_in[13];
  const float* ln1_b = (const float*)d_in[14];
  const float* ln2_s = (const float*)d_in[15];
  const float* ln2_b = (const float*)d_in[16];
  const float* lat_w = (const float*)d_in[17];
  const float* lat_b = (const float*)d_in[18];
  const float* b1_w  = (const float*)d_in[19];
  const float* b1_b  = (const float*)d_in[20];
  const float* b2_w  = (const float*)d_in[21];
  const float* b2_b  = (const float*)d_in[22];

  float* ws = (float*)d_ws;
  float* h      = ws;                              // N*D f32
  float* tmp    = h + (size_t)N * D;               // 2*N*D f32 (ff2 half-K partials)
  int*  starts  = (int*)(tmp + (size_t)2 * N * D); // 32 ints
  int*  meta    = starts + 32;                     // 448 ints
  short* hb     = (short*)(meta + 448);            // N*D bf16
  short* qkvb   = hb + (size_t)N * D;              // N*3D bf16 (V cols unused)
  short* vtg    = qkvb + (size_t)N * 3 * D;        // 256*2048 bf16 (V^T per layer)
  short* qkv_t  = vtg + (size_t)256 * 2048;
  short* out_t  = qkv_t + (size_t)L * 768 * 256;
  short* ff1_t  = out_t + (size_t)L * 256 * 256;
  short* ff2_t  = ff1_t + (size_t)L * 1024 * 256;
  short* b1_t   = ff2_t + (size_t)L * 256 * 1024;
  short* lat_t  = b1_t + (size_t)128 * 256;

  float* beta_out = (float*)d_out;
  float* lat_out  = beta_out + N;

  pack_inproj<<<3113 + 2048, 256, 0, stream>>>(
      qkv_w, out_w, ff1_w, ff2_w, b1_w, lat_w,
      qkv_t, out_t, ff1_t, ff2_t, b1_t, lat_t,
      batch, starts, meta, x, Wi, bi, h, hb);

  for (int l = 0; l < L; ++l) {
    // qkv = h @ qkv_w + b -> bf16 Q,K (+ coalesced V^T)
    gemm_qkv<<<dim3(12, 32), 256, 0, stream>>>(
        hb, qkv_t + (size_t)l * 768 * 256, qkv_b + (size_t)l * 768,
        qkvb, vtg, 768, 256);
    // attention + out-proj + residual + LN1
    attn_fused<<<144, 512, 0, stream>>>(
        qkvb, vtg, meta, out_t + (size_t)l * 256 * 256, out_b + (size_t)l * 256,
        ln1_s + (size_t)l * D, ln1_b + (size_t)l * D, h, hb);
    // ff1+relu+ff2-half-K -> 2 f32 partials (grid 128 x 2 = 2 waves/SIMD)
    ff_semi<<<dim3(128, 2), 512, 0, stream>>>(
        hb, ff1_t + (size_t)l * FF * 256, ff1_b + (size_t)l * FF,
        ff2_t + (size_t)l * 256 * FF, ff2_b + (size_t)l * 256, tmp);
    // residual + 2 partials + LN2
    ln_kernel<2><<<N / 4, 256, 0, stream>>>(
        h, tmp, ln2_s + (size_t)l * D, ln2_b + (size_t)l * D, h, hb);
  }

  heads_kernel<<<160, 256, 0, stream>>>(hb, lat_t, lat_b, lat_out,
                                        b1_t, b1_b, b2_w, b2_b, beta_out);
}

// Round 18
// 190.951 us; speedup vs baseline: 1.4917x; 1.1890x over previous
//
#include <hip/hip_runtime.h>
#include <hip/hip_bf16.h>

typedef __attribute__((ext_vector_type(8))) short bf16x8;
typedef __attribute__((ext_vector_type(4))) float f32x4;

// ---------------- helpers ----------------
__device__ inline float wave_sum64(float v) {
#pragma unroll
  for (int m = 32; m >= 1; m >>= 1) v += __shfl_xor(v, m, 64);
  return v;
}
__device__ inline ushort f2bf(float f) {  // RNE float->bf16
  uint u = __float_as_uint(f);
  return (ushort)((u + 0x7FFFu + ((u >> 16) & 1u)) >> 16);
}

// ---------------- weight pack + starts/meta + input projection (one dispatch) ----------------
__global__ __launch_bounds__(256) void pack_inproj(
    const float* __restrict__ qkv_w, const float* __restrict__ out_w,
    const float* __restrict__ ff1_w, const float* __restrict__ ff2_w,
    const float* __restrict__ b1_w, const float* __restrict__ lat_w,
    short* __restrict__ qkv_t, short* __restrict__ out_t,
    short* __restrict__ ff1_t, short* __restrict__ ff2_t,
    short* __restrict__ b1_t, short* __restrict__ lat_t,
    const int* __restrict__ batch, int* __restrict__ starts, int* __restrict__ meta,
    const float* __restrict__ x, const float* __restrict__ Wi,
    const float* __restrict__ bi, float* __restrict__ h, short* __restrict__ hb) {
  int t = blockIdx.x;
  __shared__ float tile[32][33];

  if (t >= 3113) {  // input projection: one row per block
    const int row = t - 3113;
    const int j = threadIdx.x;
    float* xs = &tile[0][0];
    if (j < 16) xs[j] = x[(size_t)row * 16 + j];
    __syncthreads();
    float acc = bi[j];
#pragma unroll
    for (int k = 0; k < 16; ++k) acc += xs[k] * Wi[k * 256 + j];
    h[(size_t)row * 256 + j] = acc;
    hb[(size_t)row * 256 + j] = (short)f2bf(acc);
    return;
  }
  if (t == 3112) {  // graph boundaries + graph-aligned 16-row tile list
    for (int i = threadIdx.x; i < 2048; i += 256) {
      int b = batch[i];
      if (i == 0) {
        for (int g = 0; g <= b; ++g) starts[g] = 0;
      } else {
        int bp = batch[i - 1];
        for (int g = bp + 1; g <= b; ++g) starts[g] = i;
      }
      if (i == 2047) {
        for (int g = b + 1; g <= 16; ++g) starts[g] = 2048;
      }
    }
    __syncthreads();
    if (threadIdx.x == 0) {
      int nt = 0;
      for (int g = 0; g < 16; ++g) {
        const int js = starts[g], je = starts[g + 1];
        for (int q0 = js; q0 < je; q0 += 16) {
          meta[1 + nt * 3] = q0;
          meta[2 + nt * 3] = js;
          meta[3 + nt * 3] = je;
          ++nt;
        }
      }
      meta[0] = nt;
    }
    return;
  }
  const float* src;
  short* dst;
  int Kd, Nd, rem;
  if (t < 768) {
    int l = t / 192; rem = t % 192; Kd = 256; Nd = 768;
    src = qkv_w + (size_t)l * Kd * Nd; dst = qkv_t + (size_t)l * Nd * Kd;
  } else if (t < 1024) {
    t -= 768; int l = t / 64; rem = t % 64; Kd = 256; Nd = 256;
    src = out_w + (size_t)l * Kd * Nd; dst = out_t + (size_t)l * Nd * Kd;
  } else if (t < 2048) {
    t -= 1024; int l = t / 256; rem = t % 256; Kd = 256; Nd = 1024;
    src = ff1_w + (size_t)l * Kd * Nd; dst = ff1_t + (size_t)l * Nd * Kd;
  } else if (t < 3072) {
    t -= 2048; int l = t / 256; rem = t % 256; Kd = 1024; Nd = 256;
    src = ff2_w + (size_t)l * Kd * Nd; dst = ff2_t + (size_t)l * Nd * Kd;
  } else if (t < 3104) {
    rem = t - 3072; Kd = 256; Nd = 128; src = b1_w; dst = b1_t;
  } else {
    rem = t - 3104; Kd = 256; Nd = 32; src = lat_w; dst = lat_t;
  }
  const int ntn = Nd / 32;
  const int kt = rem / ntn, nt = rem % ntn;
  const int tx = threadIdx.x & 31, ty = threadIdx.x >> 5;
#pragma unroll
  for (int r = 0; r < 4; ++r) {
    int k = kt * 32 + ty + r * 8;
    tile[ty + r * 8][tx] = src[(size_t)k * Nd + nt * 32 + tx];
  }
  __syncthreads();
#pragma unroll
  for (int r = 0; r < 4; ++r) {
    int n = nt * 32 + ty + r * 8;
    dst[(size_t)n * Kd + kt * 32 + tx] = (short)f2bf(tile[tx][ty + r * 8]);
  }
}

// ---------------- MFMA bf16 GEMM, BK=128 (r11-proven) ----------------
// P=0: bf16 out; P>0: split-K (blockIdx.z) f32 partials at Cf + z*M*N (bias z==0).
// VT=1 (qkv): V cols (bn>=8) go ONLY to V^T [256][2048] via LDS transpose.
template <int ACT, int P, int VT>
__global__ __launch_bounds__(256) void gemm_bf16(
    const short* __restrict__ A, const short* __restrict__ Bt,
    const float* __restrict__ bias, float* __restrict__ Cf, short* __restrict__ Cb,
    short* __restrict__ vtg, int M, int N, int K, int kpb) {
  __shared__ short As[64 * 128];
  __shared__ short Bs[64 * 128];

  const int t = threadIdx.x;
  const int bm = blockIdx.y, bn = blockIdx.x, bz = blockIdx.z;
  const int srow = t >> 2, sq = t & 3;
  const int lane = t & 63, wid = t >> 6;
  const int wr = wid >> 1, wc = wid & 1;
  const int fr = lane & 15, fs = lane >> 4;
  const int rx = srow & 7;

  f32x4 acc[2][2];
#pragma unroll
  for (int m = 0; m < 2; ++m)
#pragma unroll
    for (int n = 0; n < 2; ++n) acc[m][n] = (f32x4){0.f, 0.f, 0.f, 0.f};

  const int kbase = bz * kpb;
  const short* ap = A + (size_t)(bm * 64 + srow) * K + kbase;
  const int ng = bn * 64 + srow;
  const short* bp = Bt + (size_t)ng * K + kbase;
  const int ar0 = wr * 32 + fr, ar1 = ar0 + 16;
  const int bc0 = wc * 32 + fr, bc1 = bc0 + 16;

  for (int k0 = 0; k0 < kpb; k0 += 128) {
    bf16x8 av[4], bv[4];
#pragma unroll
    for (int i = 0; i < 4; ++i) av[i] = *(const bf16x8*)(ap + k0 + (sq * 4 + i) * 8);
    if (ng < N) {
#pragma unroll
      for (int i = 0; i < 4; ++i) bv[i] = *(const bf16x8*)(bp + k0 + (sq * 4 + i) * 8);
    } else {
#pragma unroll
      for (int i = 0; i < 4; ++i) bv[i] = (bf16x8){0, 0, 0, 0, 0, 0, 0, 0};
    }
    __syncthreads();
#pragma unroll
    for (int i = 0; i < 4; ++i) {
      const int s = sq * 4 + i;
      *(bf16x8*)(As + srow * 128 + ((s ^ rx) * 8)) = av[i];
      *(bf16x8*)(Bs + srow * 128 + ((s ^ rx) * 8)) = bv[i];
    }
    __syncthreads();
#pragma unroll
    for (int ks = 0; ks < 4; ++ks) {
      const int u = ks * 4 + fs;
      bf16x8 a0 = *(const bf16x8*)(As + ar0 * 128 + ((u ^ (ar0 & 7)) * 8));
      bf16x8 a1 = *(const bf16x8*)(As + ar1 * 128 + ((u ^ (ar1 & 7)) * 8));
      bf16x8 b0 = *(const bf16x8*)(Bs + bc0 * 128 + ((u ^ (bc0 & 7)) * 8));
      bf16x8 b1 = *(const bf16x8*)(Bs + bc1 * 128 + ((u ^ (bc1 & 7)) * 8));
      acc[0][0] = __builtin_amdgcn_mfma_f32_16x16x32_bf16(a0, b0, acc[0][0], 0, 0, 0);
      acc[0][1] = __builtin_amdgcn_mfma_f32_16x16x32_bf16(a0, b1, acc[0][1], 0, 0, 0);
      acc[1][0] = __builtin_amdgcn_mfma_f32_16x16x32_bf16(a1, b0, acc[1][0], 0, 0, 0);
      acc[1][1] = __builtin_amdgcn_mfma_f32_16x16x32_bf16(a1, b1, acc[1][1], 0, 0, 0);
    }
  }

  if (P == 0) {
    if (!(VT && bn >= 8)) {
#pragma unroll
      for (int n = 0; n < 2; ++n) {
        const int col = bn * 64 + wc * 32 + n * 16 + fr;
        if (col < N) {
          const float bvv = bias[col];
#pragma unroll
          for (int m = 0; m < 2; ++m) {
            const int rbase = bm * 64 + wr * 32 + m * 16 + fs * 4;
#pragma unroll
            for (int j = 0; j < 4; ++j) {
              float v = acc[m][n][j] + bvv;
              if (ACT == 1) v = fmaxf(v, 0.f);
              Cb[(size_t)(rbase + j) * N + col] = (short)f2bf(v);
            }
          }
        }
      }
    }
    if (VT && bn >= 8) {  // coalesced V^T epilogue for qkv cols [512,768)
      short* tr = As;  // reuse LDS: [64 cols][68 rows]
      __syncthreads();
#pragma unroll
      for (int n = 0; n < 2; ++n) {
        const int c = wc * 32 + n * 16 + fr;
        const float bvv = bias[bn * 64 + c];
#pragma unroll
        for (int m = 0; m < 2; ++m)
#pragma unroll
          for (int j = 0; j < 4; ++j) {
            const int r = wr * 32 + m * 16 + fs * 4 + j;
            tr[c * 68 + r] = (short)f2bf(acc[m][n][j] + bvv);
          }
      }
      __syncthreads();
      const int tx = t & 63, ty = t >> 6;
      const int d0 = bn * 64 - 512, rb = bm * 64;
#pragma unroll
      for (int r = 0; r < 16; ++r) {
        const int d = ty * 16 + r;
        vtg[(size_t)(d0 + d) * 2048 + rb + tx] = tr[d * 68 + tx];
      }
    }
  } else {
    // split-K f32 partial store (no sync; consumer ln_kernel sums)
#pragma unroll
    for (int n = 0; n < 2; ++n) {
      const int col = bn * 64 + wc * 32 + n * 16 + fr;
      const float bvv = (bz == 0) ? bias[col] : 0.f;
#pragma unroll
      for (int m = 0; m < 2; ++m) {
        const int rbase = bm * 64 + wr * 32 + m * 16 + fs * 4;
#pragma unroll
        for (int j = 0; j < 4; ++j) {
          Cf[(size_t)(bz * M + rbase + j) * N + col] = acc[m][n][j] + bvv;
        }
      }
    }
  }
}

// ---------------- attention + full out-proj + residual + LN1, one block per q-tile ----------------
// 512 threads = 8 waves; wave w = head w (r15-proven). O -> Ot LDS; barrier; each wave
// does 2 col-tiles of out-proj at full K=256; block applies residual + LN via LDS reduce.
__global__ __launch_bounds__(512) void attn_fused(
    const short* __restrict__ qkv, const short* __restrict__ vtg,
    const int* __restrict__ meta, const short* __restrict__ out_t,
    const float* __restrict__ outb, const float* __restrict__ lns,
    const float* __restrict__ lnb, float* __restrict__ h, short* __restrict__ hb) {
  __shared__ short Ot[8][16][40];
  __shared__ float redS[8][16], redQ[8][16];
  const int w = threadIdx.x >> 6;  // wave = head
  const int tile = blockIdx.x;
  const bool active = (tile < meta[0]);
  const int lane = threadIdx.x & 63;
  const int fr = lane & 15, fs = lane >> 4;
  const int q0 = active ? meta[1 + tile * 3] : 0;
  const int js = active ? meta[2 + tile * 3] : 0;
  const int je = active ? meta[3 + tile * 3] : 0;
  const int jbase = js & ~15;
  const int njt = active ? ((je - jbase + 15) >> 4) : 0;  // <=16
  const float scale = 0.17677669529663687f;  // 1/sqrt(32)

  const int qrow = min(q0 + fr, 2047);
  const bf16x8 qf = *(const bf16x8*)(qkv + (size_t)qrow * 768 + w * 32 + fs * 8);
  const int jeq = (q0 + fr < je) ? je : 0;

  f32x4 s[16];
#pragma unroll
  for (int jt = 0; jt < 16; ++jt)
    s[jt] = (f32x4){-3.0e38f, -3.0e38f, -3.0e38f, -3.0e38f};

#pragma unroll
  for (int jt = 0; jt < 16; ++jt) {
    if (jt < njt) {
      const int krow = min(jbase + jt * 16 + fr, 2047);
      const bf16x8 kf = *(const bf16x8*)(qkv + (size_t)krow * 768 + 256 + w * 32 + fs * 8);
      s[jt] = __builtin_amdgcn_mfma_f32_16x16x32_bf16(
          kf, qf, (f32x4){0.f, 0.f, 0.f, 0.f}, 0, 0, 0);
    }
  }
  float mx = -3.0e38f;
#pragma unroll
  for (int jt = 0; jt < 16; ++jt) {
    if (jt < njt) {
#pragma unroll
      for (int jj = 0; jj < 4; ++jj) {
        const int j = jbase + jt * 16 + fs * 4 + jj;
        const bool valid = (j >= js) && (j < jeq);
        s[jt][jj] = valid ? s[jt][jj] * scale : -3.0e38f;
        mx = fmaxf(mx, s[jt][jj]);
      }
    }
  }
  mx = fmaxf(mx, __shfl_xor(mx, 16, 64));
  mx = fmaxf(mx, __shfl_xor(mx, 32, 64));
  float l = 0.f;
#pragma unroll
  for (int jt = 0; jt < 16; ++jt) {
#pragma unroll
    for (int jj = 0; jj < 4; ++jj) {
      const float p = __expf(s[jt][jj] - mx);
      s[jt][jj] = p;
      l += p;
    }
  }
  l += __shfl_xor(l, 16, 64);
  l += __shfl_xor(l, 32, 64);

  f32x4 oa[2];
  oa[0] = (f32x4){0.f, 0.f, 0.f, 0.f};
  oa[1] = (f32x4){0.f, 0.f, 0.f, 0.f};
#pragma unroll
  for (int p2 = 0; p2 < 8; ++p2) {
    if (p2 * 2 < njt) {
      bf16x8 pa;
      pa[0] = (short)f2bf(s[p2 * 2][0]);     pa[1] = (short)f2bf(s[p2 * 2][1]);
      pa[2] = (short)f2bf(s[p2 * 2][2]);     pa[3] = (short)f2bf(s[p2 * 2][3]);
      pa[4] = (short)f2bf(s[p2 * 2 + 1][0]); pa[5] = (short)f2bf(s[p2 * 2 + 1][1]);
      pa[6] = (short)f2bf(s[p2 * 2 + 1][2]); pa[7] = (short)f2bf(s[p2 * 2 + 1][3]);
      const int jb0 = min(jbase + p2 * 32 + fs * 4, 2044);
      const int jb1 = min(jbase + p2 * 32 + 16 + fs * 4, 2044);
#pragma unroll
      for (int nt = 0; nt < 2; ++nt) {
        const short* vrow = vtg + (size_t)(w * 32 + nt * 16 + fr) * 2048;
        const short4 v0 = *(const short4*)(vrow + jb0);
        const short4 v1 = *(const short4*)(vrow + jb1);
        bf16x8 vf;
        vf[0] = v0.x; vf[1] = v0.y; vf[2] = v0.z; vf[3] = v0.w;
        vf[4] = v1.x; vf[5] = v1.y; vf[6] = v1.z; vf[7] = v1.w;
        oa[nt] = __builtin_amdgcn_mfma_f32_16x16x32_bf16(pa, vf, oa[nt], 0, 0, 0);
      }
    }
  }

#pragma unroll
  for (int jj = 0; jj < 4; ++jj) {
    const float lq = __shfl(l, fs * 4 + jj, 64);
    const float inv = (lq > 0.f) ? (1.f / lq) : 0.f;
    const int q = fs * 4 + jj;
    Ot[w][q][fr] = (short)f2bf(oa[0][jj] * inv);
    Ot[w][q][16 + fr] = (short)f2bf(oa[1][jj] * inv);
  }
  __syncthreads();

  // out-proj, full K=256: wave w owns col-tiles 2w, 2w+1
  f32x4 acc2[2];
  acc2[0] = (f32x4){0.f, 0.f, 0.f, 0.f};
  acc2[1] = (f32x4){0.f, 0.f, 0.f, 0.f};
#pragma unroll
  for (int ks = 0; ks < 8; ++ks) {
    const bf16x8 afrag = *(const bf16x8*)&Ot[ks][fr][fs * 8];
#pragma unroll
    for (int nt2 = 0; nt2 < 2; ++nt2) {
      const int col_row = (w * 2 + nt2) * 16 + fr;
      const bf16x8 bfrag =
          *(const bf16x8*)(out_t + (size_t)col_row * 256 + ks * 32 + fs * 8);
      acc2[nt2] = __builtin_amdgcn_mfma_f32_16x16x32_bf16(afrag, bfrag, acc2[nt2], 0, 0, 0);
    }
  }

  float d[2][4], ps[4], pq[4];
#pragma unroll
  for (int jj = 0; jj < 4; ++jj) {
    const int node = q0 + fs * 4 + jj;
    const int noder = min(node, 2047);
#pragma unroll
    for (int nt2 = 0; nt2 < 2; ++nt2) {
      const int col = w * 32 + nt2 * 16 + fr;
      d[nt2][jj] = acc2[nt2][jj] + outb[col] + h[(size_t)noder * 256 + col];
    }
    ps[jj] = d[0][jj] + d[1][jj];
    pq[jj] = d[0][jj] * d[0][jj] + d[1][jj] * d[1][jj];
#pragma unroll
    for (int m = 1; m <= 8; m <<= 1) {
      ps[jj] += __shfl_xor(ps[jj], m, 64);
      pq[jj] += __shfl_xor(pq[jj], m, 64);
    }
  }
  if (fr == 0) {
#pragma unroll
    for (int jj = 0; jj < 4; ++jj) {
      redS[w][fs * 4 + jj] = ps[jj];
      redQ[w][fs * 4 + jj] = pq[jj];
    }
  }
  __syncthreads();

#pragma unroll
  for (int jj = 0; jj < 4; ++jj) {
    const int row = fs * 4 + jj;
    float S = 0.f, Q = 0.f;
#pragma unroll
    for (int ww = 0; ww < 8; ++ww) { S += redS[ww][row]; Q += redQ[ww][row]; }
    const float mean = S * (1.f / 256.f);
    const float var = Q * (1.f / 256.f) - mean * mean;
    const float rs = rsqrtf(var + 1e-5f);
    const int node = q0 + row;
    if (active && node < je) {
#pragma unroll
      for (int nt2 = 0; nt2 < 2; ++nt2) {
        const int col = w * 32 + nt2 * 16 + fr;
        const float o = (d[nt2][jj] - mean) * rs * lns[col] + lnb[col];
        h[(size_t)node * 256 + col] = o;
        hb[(size_t)node * 256 + col] = (short)f2bf(o);
      }
    }
  }
}

// ---------------- fused residual + P-partial sum + LayerNorm; writes f32 + bf16 ----------------
template <int P>
__global__ __launch_bounds__(256) void ln_kernel(
    const float* __restrict__ base, const float* __restrict__ delta,
    const float* __restrict__ s, const float* __restrict__ b,
    float* __restrict__ outf, short* __restrict__ outb) {
  const int row = blockIdx.x * 4 + (threadIdx.x >> 6);
  const int lane = threadIdx.x & 63;
  float4 v = *(const float4*)(base + (size_t)row * 256 + lane * 4);
#pragma unroll
  for (int p = 0; p < P; ++p) {
    const float4 xb = *(const float4*)(delta + (size_t)(p * 2048 + row) * 256 + lane * 4);
    v.x += xb.x; v.y += xb.y; v.z += xb.z; v.w += xb.w;
  }
  float sum = wave_sum64(v.x + v.y + v.z + v.w);
  const float mean = sum * (1.f / 256.f);
  float4 d = make_float4(v.x - mean, v.y - mean, v.z - mean, v.w - mean);
  float sq = wave_sum64(d.x * d.x + d.y * d.y + d.z * d.z + d.w * d.w);
  const float rs = rsqrtf(sq * (1.f / 256.f) + 1e-5f);
  const float4 sv = *(const float4*)(s + lane * 4);
  const float4 bv = *(const float4*)(b + lane * 4);
  float4 o = make_float4(d.x * rs * sv.x + bv.x, d.y * rs * sv.y + bv.y,
                         d.z * rs * sv.z + bv.z, d.w * rs * sv.w + bv.w);
  *(float4*)(outf + (size_t)row * 256 + lane * 4) = o;
  short4 ob;
  ob.x = (short)f2bf(o.x); ob.y = (short)f2bf(o.y);
  ob.z = (short)f2bf(o.z); ob.w = (short)f2bf(o.w);
  *(short4*)(outb + (size_t)row * 256 + lane * 4) = ob;
}

// ---------------- heads: lat (blocks 0..31) + beta (blocks 32..159), one dispatch ----------------
__global__ __launch_bounds__(256) void heads_kernel(
    const short* __restrict__ A, const short* __restrict__ lat_t,
    const float* __restrict__ lat_b, float* __restrict__ lat_out,
    const short* __restrict__ b1_t, const float* __restrict__ b1b,
    const float* __restrict__ w2, const float* __restrict__ b2b,
    float* __restrict__ beta) {
  __shared__ short smem[64 * 128 * 2];
  const int t = threadIdx.x;
  const int lane = t & 63, w = t >> 6;
  const int fr = lane & 15, fs = lane >> 4;

  if (blockIdx.x < 32) {  // ---- lat tile: GEMM (N=32, K=256) + row-normalize ----
    short* As = smem;
    short* Bs = smem + 64 * 128;
    const int bm = blockIdx.x;
    const int srow = t >> 2, sq = t & 3;
    const int rx = srow & 7;
    f32x4 acc[2];
    acc[0] = (f32x4){0.f, 0.f, 0.f, 0.f};
    acc[1] = (f32x4){0.f, 0.f, 0.f, 0.f};
    const short* ap = A + (size_t)(bm * 64 + srow) * 256;
    const short* bp = lat_t + (size_t)srow * 256;
    const int ar = w * 16 + fr;
    for (int k0 = 0; k0 < 256; k0 += 128) {
      bf16x8 av[4], bv[4];
#pragma unroll
      for (int i = 0; i < 4; ++i) av[i] = *(const bf16x8*)(ap + k0 + (sq * 4 + i) * 8);
      if (srow < 32) {
#pragma unroll
        for (int i = 0; i < 4; ++i) bv[i] = *(const bf16x8*)(bp + k0 + (sq * 4 + i) * 8);
      } else {
#pragma unroll
        for (int i = 0; i < 4; ++i) bv[i] = (bf16x8){0, 0, 0, 0, 0, 0, 0, 0};
      }
      __syncthreads();
#pragma unroll
      for (int i = 0; i < 4; ++i) {
        const int s = sq * 4 + i;
        *(bf16x8*)(As + srow * 128 + ((s ^ rx) * 8)) = av[i];
        *(bf16x8*)(Bs + srow * 128 + ((s ^ rx) * 8)) = bv[i];
      }
      __syncthreads();
#pragma unroll
      for (int ks = 0; ks < 4; ++ks) {
        const int u = ks * 4 + fs;
        bf16x8 a0 = *(const bf16x8*)(As + ar * 128 + ((u ^ (ar & 7)) * 8));
        bf16x8 b0 = *(const bf16x8*)(Bs + fr * 128 + ((u ^ (fr & 7)) * 8));
        bf16x8 b1 = *(const bf16x8*)(Bs + (16 + fr) * 128 + ((u ^ ((16 + fr) & 7)) * 8));
        acc[0] = __builtin_amdgcn_mfma_f32_16x16x32_bf16(a0, b0, acc[0], 0, 0, 0);
        acc[1] = __builtin_amdgcn_mfma_f32_16x16x32_bf16(a0, b1, acc[1], 0, 0, 0);
      }
    }
    const float b0v = lat_b[fr], b1v = lat_b[16 + fr];
#pragma unroll
    for (int j = 0; j < 4; ++j) {
      const int row = bm * 64 + w * 16 + fs * 4 + j;
      float v0 = acc[0][j] + b0v;
      float v1 = acc[1][j] + b1v;
      float ss = v0 * v0 + v1 * v1;
      ss += __shfl_xor(ss, 1, 64);
      ss += __shfl_xor(ss, 2, 64);
      ss += __shfl_xor(ss, 4, 64);
      ss += __shfl_xor(ss, 8, 64);
      const float inv = 5.656854249492381f / fmaxf(sqrtf(ss), 1e-12f);
      lat_out[(size_t)row * 32 + fr] = v0 * inv;
      lat_out[(size_t)row * 32 + 16 + fr] = v1 * inv;
    }
  } else {  // ---- beta: sigmoid(relu(h@W1+b1)@w2+b2), 16 rows per block ----
    float* red = (float*)smem;
    const int rb = (blockIdx.x - 32) * 16;
    f32x4 acc[2];
    acc[0] = (f32x4){0.f, 0.f, 0.f, 0.f};
    acc[1] = (f32x4){0.f, 0.f, 0.f, 0.f};
    const short* ap = A + (size_t)(rb + fr) * 256;
    const short* bp = b1_t + (size_t)(w * 32 + fr) * 256;
    for (int k0 = 0; k0 < 256; k0 += 32) {
      const bf16x8 af = *(const bf16x8*)(ap + k0 + fs * 8);
#pragma unroll
      for (int n = 0; n < 2; ++n) {
        const bf16x8 bf = *(const bf16x8*)(bp + (size_t)n * 16 * 256 + k0 + fs * 8);
        acc[n] = __builtin_amdgcn_mfma_f32_16x16x32_bf16(af, bf, acc[n], 0, 0, 0);
      }
    }
    const int c0 = w * 32 + fr, c1 = c0 + 16;
    const float b0 = b1b[c0], b1 = b1b[c1];
    const float w0 = w2[c0], w1 = w2[c1];
    float part[4];
#pragma unroll
    for (int j = 0; j < 4; ++j) {
      const float d0 = fmaxf(acc[0][j] + b0, 0.f);
      const float d1 = fmaxf(acc[1][j] + b1, 0.f);
      part[j] = d0 * w0 + d1 * w1;
#pragma unroll
      for (int m = 1; m <= 8; m <<= 1) part[j] += __shfl_xor(part[j], m, 64);
    }
    if (fr == 0) {
#pragma unroll
      for (int j = 0; j < 4; ++j) red[w * 16 + fs * 4 + j] = part[j];
    }
    __syncthreads();
    if (t < 16) {
      const float S = red[t] + red[16 + t] + red[32 + t] + red[48 + t] + b2b[0];
      float sgm = 1.f / (1.f + __expf(-S));
      sgm = fminf(fmaxf(sgm, 1e-6f), 1.f - 1e-6f);
      beta[rb + t] = sgm;
    }
  }
}

// ---------------- launch ----------------
extern "C" void kernel_launch(void* const* d_in, const int* in_sizes, int n_in,
                              void* d_out, int out_size, void* d_ws, size_t ws_size,
                              hipStream_t stream) {
  const int N = 2048, D = 256, FF = 1024, L = 4;

  const float* x     = (const float*)d_in[0];
  const int*   batch = (const int*)d_in[2];
  const float* Wi    = (const float*)d_in[3];
  const float* bi    = (const float*)d_in[4];
  const float* qkv_w = (const float*)d_in[5];
  const float* qkv_b = (const float*)d_in[6];
  const float* out_w = (const float*)d_in[7];
  const float* out_b = (const float*)d_in[8];
  const float* ff1_w = (const float*)d_in[9];
  const float* ff1_b = (const float*)d_in[10];
  const float* ff2_w = (const float*)d_in[11];
  const float* ff2_b = (const float*)d_in[12];
  const float* ln1_s = (const float*)d_in[13];
  const float* ln1_b = (const float*)d_in[14];
  const float* ln2_s = (const float*)d_in[15];
  const float* ln2_b = (const float*)d_in[16];
  const float* lat_w = (const float*)d_in[17];
  const float* lat_b = (const float*)d_in[18];
  const float* b1_w  = (const float*)d_in[19];
  const float* b1_b  = (const float*)d_in[20];
  const float* b2_w  = (const float*)d_in[21];
  const float* b2_b  = (const float*)d_in[22];

  float* ws = (float*)d_ws;
  float* h      = ws;                              // N*D f32
  float* tmp    = h + (size_t)N * D;               // 4*N*D f32 (ff2 split-K partials)
  int*  starts  = (int*)(tmp + (size_t)4 * N * D); // 32 ints
  int*  meta    = starts + 32;                     // 448 ints
  short* hb     = (short*)(meta + 448);            // N*D bf16
  short* qkvb   = hb + (size_t)N * D;              // N*3D bf16 (V cols unused)
  short* ffb    = qkvb + (size_t)N * 3 * D;        // N*FF bf16
  short* vtg    = ffb + (size_t)N * FF;            // 256*2048 bf16 (V^T per layer)
  short* qkv_t  = vtg + (size_t)256 * 2048;
  short* out_t  = qkv_t + (size_t)L * 768 * 256;
  short* ff1_t  = out_t + (size_t)L * 256 * 256;
  short* ff2_t  = ff1_t + (size_t)L * 1024 * 256;
  short* b1_t   = ff2_t + (size_t)L * 256 * 1024;
  short* lat_t  = b1_t + (size_t)128 * 256;

  float* beta_out = (float*)d_out;
  float* lat_out  = beta_out + N;

  pack_inproj<<<3113 + 2048, 256, 0, stream>>>(
      qkv_w, out_w, ff1_w, ff2_w, b1_w, lat_w,
      qkv_t, out_t, ff1_t, ff2_t, b1_t, lat_t,
      batch, starts, meta, x, Wi, bi, h, hb);

  for (int l = 0; l < L; ++l) {
    // qkv = h @ qkv_w + b -> bf16 Q,K (+ coalesced V^T)
    gemm_bf16<0, 0, 1><<<dim3(12, 32, 1), 256, 0, stream>>>(
        hb, qkv_t + (size_t)l * 768 * 256, qkv_b + (size_t)l * 768,
        nullptr, qkvb, vtg, N, 768, 256, 256);
    // attention + out-proj + residual + LN1
    attn_fused<<<144, 512, 0, stream>>>(
        qkvb, vtg, meta, out_t + (size_t)l * 256 * 256, out_b + (size_t)l * 256,
        ln1_s + (size_t)l * D, ln1_b + (size_t)l * D, h, hb);
    // ff1 = relu(h @ ff1_w + b) -> bf16
    gemm_bf16<1, 0, 0><<<dim3(16, 32, 1), 256, 0, stream>>>(
        hb, ff1_t + (size_t)l * FF * 256, ff1_b + (size_t)l * FF,
        nullptr, ffb, nullptr, N, FF, 256, 256);
    // ff2 split-K=4 -> f32 partials
    gemm_bf16<0, 4, 0><<<dim3(4, 32, 4), 256, 0, stream>>>(
        ffb, ff2_t + (size_t)l * 256 * FF, ff2_b + (size_t)l * 256,
        tmp, nullptr, nullptr, N, 256, 1024, 256);
    // residual + 4 partials + LN2
    ln_kernel<4><<<N / 4, 256, 0, stream>>>(
        h, tmp, ln2_s + (size_t)l * D, ln2_b + (size_t)l * D, h, hb);
  }

  heads_kernel<<<160, 256, 0, stream>>>(hb, lat_t, lat_b, lat_out,
                                        b1_t, b1_b, b2_w, b2_b, beta_out);
}

// Round 19
// 184.033 us; speedup vs baseline: 1.5477x; 1.0376x over previous
//
#include <hip/hip_runtime.h>
#include <hip/hip_bf16.h>

typedef __attribute__((ext_vector_type(8))) short bf16x8;
typedef __attribute__((ext_vector_type(4))) float f32x4;

// ---------------- helpers ----------------
__device__ inline float wave_sum64(float v) {
#pragma unroll
  for (int m = 32; m >= 1; m >>= 1) v += __shfl_xor(v, m, 64);
  return v;
}
__device__ inline ushort f2bf(float f) {  // RNE float->bf16
  uint u = __float_as_uint(f);
  return (ushort)((u + 0x7FFFu + ((u >> 16) & 1u)) >> 16);
}
// direct global->LDS DMA, 16B per lane; lds base must be wave-uniform
__device__ inline void gload16(const short* g, short* lds) {
  __builtin_amdgcn_global_load_lds(
      (const __attribute__((address_space(1))) void*)g,
      (__attribute__((address_space(3))) void*)lds, 16, 0, 0);
}

// ---------------- weight pack + starts/meta + input projection (one dispatch) ----------------
__global__ __launch_bounds__(256) void pack_inproj(
    const float* __restrict__ qkv_w, const float* __restrict__ out_w,
    const float* __restrict__ ff1_w, const float* __restrict__ ff2_w,
    const float* __restrict__ b1_w, const float* __restrict__ lat_w,
    short* __restrict__ qkv_t, short* __restrict__ out_t,
    short* __restrict__ ff1_t, short* __restrict__ ff2_t,
    short* __restrict__ b1_t, short* __restrict__ lat_t,
    const int* __restrict__ batch, int* __restrict__ starts, int* __restrict__ meta,
    const float* __restrict__ x, const float* __restrict__ Wi,
    const float* __restrict__ bi, float* __restrict__ h, short* __restrict__ hb) {
  int t = blockIdx.x;
  __shared__ float tile[32][33];

  if (t >= 3113) {  // input projection: one row per block
    const int row = t - 3113;
    const int j = threadIdx.x;
    float* xs = &tile[0][0];
    if (j < 16) xs[j] = x[(size_t)row * 16 + j];
    __syncthreads();
    float acc = bi[j];
#pragma unroll
    for (int k = 0; k < 16; ++k) acc += xs[k] * Wi[k * 256 + j];
    h[(size_t)row * 256 + j] = acc;
    hb[(size_t)row * 256 + j] = (short)f2bf(acc);
    return;
  }
  if (t == 3112) {  // graph boundaries + graph-aligned 16-row tile list
    for (int i = threadIdx.x; i < 2048; i += 256) {
      int b = batch[i];
      if (i == 0) {
        for (int g = 0; g <= b; ++g) starts[g] = 0;
      } else {
        int bp = batch[i - 1];
        for (int g = bp + 1; g <= b; ++g) starts[g] = i;
      }
      if (i == 2047) {
        for (int g = b + 1; g <= 16; ++g) starts[g] = 2048;
      }
    }
    __syncthreads();
    if (threadIdx.x == 0) {
      int nt = 0;
      for (int g = 0; g < 16; ++g) {
        const int js = starts[g], je = starts[g + 1];
        for (int q0 = js; q0 < je; q0 += 16) {
          meta[1 + nt * 3] = q0;
          meta[2 + nt * 3] = js;
          meta[3 + nt * 3] = je;
          ++nt;
        }
      }
      meta[0] = nt;
    }
    return;
  }
  const float* src;
  short* dst;
  int Kd, Nd, rem;
  if (t < 768) {
    int l = t / 192; rem = t % 192; Kd = 256; Nd = 768;
    src = qkv_w + (size_t)l * Kd * Nd; dst = qkv_t + (size_t)l * Nd * Kd;
  } else if (t < 1024) {
    t -= 768; int l = t / 64; rem = t % 64; Kd = 256; Nd = 256;
    src = out_w + (size_t)l * Kd * Nd; dst = out_t + (size_t)l * Nd * Kd;
  } else if (t < 2048) {
    t -= 1024; int l = t / 256; rem = t % 256; Kd = 256; Nd = 1024;
    src = ff1_w + (size_t)l * Kd * Nd; dst = ff1_t + (size_t)l * Nd * Kd;
  } else if (t < 3072) {
    t -= 2048; int l = t / 256; rem = t % 256; Kd = 1024; Nd = 256;
    src = ff2_w + (size_t)l * Kd * Nd; dst = ff2_t + (size_t)l * Nd * Kd;
  } else if (t < 3104) {
    rem = t - 3072; Kd = 256; Nd = 128; src = b1_w; dst = b1_t;
  } else {
    rem = t - 3104; Kd = 256; Nd = 32; src = lat_w; dst = lat_t;
  }
  const int ntn = Nd / 32;
  const int kt = rem / ntn, nt = rem % ntn;
  const int tx = threadIdx.x & 31, ty = threadIdx.x >> 5;
#pragma unroll
  for (int r = 0; r < 4; ++r) {
    int k = kt * 32 + ty + r * 8;
    tile[ty + r * 8][tx] = src[(size_t)k * Nd + nt * 32 + tx];
  }
  __syncthreads();
#pragma unroll
  for (int r = 0; r < 4; ++r) {
    int n = nt * 32 + ty + r * 8;
    dst[(size_t)n * Kd + kt * 32 + tx] = (short)f2bf(tile[tx][ty + r * 8]);
  }
}

// ---------------- MFMA bf16 GEMM, BK=128; staging via global_load_lds (16B) ----------------
// P=0: bf16 out; P>0: split-K (blockIdx.z) f32 partials at Cf + z*M*N (bias z==0).
// VT=1 (qkv): V cols (bn>=8) go ONLY to V^T [256][2048] via LDS transpose.
// LDS layout identical to r18 (linear dest + inverse-swizzled global source; reads
// keep the (u ^ (row&7)) swizzle) -> bit-identical math. N % 64 == 0 assumed.
template <int ACT, int P, int VT>
__global__ __launch_bounds__(256) void gemm_bf16(
    const short* __restrict__ A, const short* __restrict__ Bt,
    const float* __restrict__ bias, float* __restrict__ Cf, short* __restrict__ Cb,
    short* __restrict__ vtg, int M, int N, int K, int kpb) {
  __shared__ short As[64 * 128];
  __shared__ short Bs[64 * 128];

  const int t = threadIdx.x;
  const int bm = blockIdx.y, bn = blockIdx.x, bz = blockIdx.z;
  const int lane = t & 63, wid = t >> 6;
  const int wr = wid >> 1, wc = wid & 1;
  const int fr = lane & 15, fs = lane >> 4;

  f32x4 acc[2][2];
#pragma unroll
  for (int m = 0; m < 2; ++m)
#pragma unroll
    for (int n = 0; n < 2; ++n) acc[m][n] = (f32x4){0.f, 0.f, 0.f, 0.f};

  const int kbase = bz * kpb;
  const short* Ag = A + (size_t)bm * 64 * K + kbase;   // tile row 0
  const short* Bg = Bt + (size_t)bn * 64 * K + kbase;
  const int ri = lane >> 4;   // local row within a 4-row DMA chunk
  const int sl = lane & 15;   // linear 16B slot within row
  const int ar0 = wr * 32 + fr, ar1 = ar0 + 16;
  const int bc0 = wc * 32 + fr, bc1 = bc0 + 16;

  for (int k0 = 0; k0 < kpb; k0 += 128) {
    __syncthreads();  // prior-tile LDS reads done before DMA overwrite
#pragma unroll
    for (int c = 0; c < 4; ++c) {
      const int r0 = wid * 16 + c * 4;       // wave-uniform row base
      const int r = r0 + ri;                 // per-lane row
      const int sa = sl ^ (r & 7);           // inverse swizzle on source
      gload16(Ag + (size_t)r * K + k0 + sa * 8, As + r0 * 128);
      gload16(Bg + (size_t)r * K + k0 + sa * 8, Bs + r0 * 128);
    }
    __syncthreads();  // drains vmcnt: DMA complete before reads
#pragma unroll
    for (int ks = 0; ks < 4; ++ks) {
      const int u = ks * 4 + fs;
      bf16x8 a0 = *(const bf16x8*)(As + ar0 * 128 + ((u ^ (ar0 & 7)) * 8));
      bf16x8 a1 = *(const bf16x8*)(As + ar1 * 128 + ((u ^ (ar1 & 7)) * 8));
      bf16x8 b0 = *(const bf16x8*)(Bs + bc0 * 128 + ((u ^ (bc0 & 7)) * 8));
      bf16x8 b1 = *(const bf16x8*)(Bs + bc1 * 128 + ((u ^ (bc1 & 7)) * 8));
      acc[0][0] = __builtin_amdgcn_mfma_f32_16x16x32_bf16(a0, b0, acc[0][0], 0, 0, 0);
      acc[0][1] = __builtin_amdgcn_mfma_f32_16x16x32_bf16(a0, b1, acc[0][1], 0, 0, 0);
      acc[1][0] = __builtin_amdgcn_mfma_f32_16x16x32_bf16(a1, b0, acc[1][0], 0, 0, 0);
      acc[1][1] = __builtin_amdgcn_mfma_f32_16x16x32_bf16(a1, b1, acc[1][1], 0, 0, 0);
    }
  }

  if (P == 0) {
    if (!(VT && bn >= 8)) {
#pragma unroll
      for (int n = 0; n < 2; ++n) {
        const int col = bn * 64 + wc * 32 + n * 16 + fr;
        const float bvv = bias[col];
#pragma unroll
        for (int m = 0; m < 2; ++m) {
          const int rbase = bm * 64 + wr * 32 + m * 16 + fs * 4;
#pragma unroll
          for (int j = 0; j < 4; ++j) {
            float v = acc[m][n][j] + bvv;
            if (ACT == 1) v = fmaxf(v, 0.f);
            Cb[(size_t)(rbase + j) * N + col] = (short)f2bf(v);
          }
        }
      }
    }
    if (VT && bn >= 8) {  // coalesced V^T epilogue for qkv cols [512,768)
      short* tr = As;  // reuse LDS: [64 cols][68 rows]
      __syncthreads();
#pragma unroll
      for (int n = 0; n < 2; ++n) {
        const int c = wc * 32 + n * 16 + fr;
        const float bvv = bias[bn * 64 + c];
#pragma unroll
        for (int m = 0; m < 2; ++m)
#pragma unroll
          for (int j = 0; j < 4; ++j) {
            const int r = wr * 32 + m * 16 + fs * 4 + j;
            tr[c * 68 + r] = (short)f2bf(acc[m][n][j] + bvv);
          }
      }
      __syncthreads();
      const int tx = t & 63, ty = t >> 6;
      const int d0 = bn * 64 - 512, rb = bm * 64;
#pragma unroll
      for (int r = 0; r < 16; ++r) {
        const int d = ty * 16 + r;
        vtg[(size_t)(d0 + d) * 2048 + rb + tx] = tr[d * 68 + tx];
      }
    }
  } else {
    // split-K f32 partial store (no sync; consumer ln_kernel sums)
#pragma unroll
    for (int n = 0; n < 2; ++n) {
      const int col = bn * 64 + wc * 32 + n * 16 + fr;
      const float bvv = (bz == 0) ? bias[col] : 0.f;
#pragma unroll
      for (int m = 0; m < 2; ++m) {
        const int rbase = bm * 64 + wr * 32 + m * 16 + fs * 4;
#pragma unroll
        for (int j = 0; j < 4; ++j) {
          Cf[(size_t)(bz * M + rbase + j) * N + col] = acc[m][n][j] + bvv;
        }
      }
    }
  }
}

// ---------------- attention + full out-proj + residual + LN1, one block per q-tile ----------------
// 512 threads = 8 waves; wave w = head w (r15-proven). O -> Ot LDS; barrier; each wave
// does 2 col-tiles of out-proj at full K=256; block applies residual + LN via LDS reduce.
__global__ __launch_bounds__(512) void attn_fused(
    const short* __restrict__ qkv, const short* __restrict__ vtg,
    const int* __restrict__ meta, const short* __restrict__ out_t,
    const float* __restrict__ outb, const float* __restrict__ lns,
    const float* __restrict__ lnb, float* __restrict__ h, short* __restrict__ hb) {
  __shared__ short Ot[8][16][40];
  __shared__ float redS[8][16], redQ[8][16];
  const int w = threadIdx.x >> 6;  // wave = head
  const int tile = blockIdx.x;
  const bool active = (tile < meta[0]);
  const int lane = threadIdx.x & 63;
  const int fr = lane & 15, fs = lane >> 4;
  const int q0 = active ? meta[1 + tile * 3] : 0;
  const int js = active ? meta[2 + tile * 3] : 0;
  const int je = active ? meta[3 + tile * 3] : 0;
  const int jbase = js & ~15;
  const int njt = active ? ((je - jbase + 15) >> 4) : 0;  // <=16
  const float scale = 0.17677669529663687f;  // 1/sqrt(32)

  const int qrow = min(q0 + fr, 2047);
  const bf16x8 qf = *(const bf16x8*)(qkv + (size_t)qrow * 768 + w * 32 + fs * 8);
  const int jeq = (q0 + fr < je) ? je : 0;

  f32x4 s[16];
#pragma unroll
  for (int jt = 0; jt < 16; ++jt)
    s[jt] = (f32x4){-3.0e38f, -3.0e38f, -3.0e38f, -3.0e38f};

#pragma unroll
  for (int jt = 0; jt < 16; ++jt) {
    if (jt < njt) {
      const int krow = min(jbase + jt * 16 + fr, 2047);
      const bf16x8 kf = *(const bf16x8*)(qkv + (size_t)krow * 768 + 256 + w * 32 + fs * 8);
      s[jt] = __builtin_amdgcn_mfma_f32_16x16x32_bf16(
          kf, qf, (f32x4){0.f, 0.f, 0.f, 0.f}, 0, 0, 0);
    }
  }
  float mx = -3.0e38f;
#pragma unroll
  for (int jt = 0; jt < 16; ++jt) {
    if (jt < njt) {
#pragma unroll
      for (int jj = 0; jj < 4; ++jj) {
        const int j = jbase + jt * 16 + fs * 4 + jj;
        const bool valid = (j >= js) && (j < jeq);
        s[jt][jj] = valid ? s[jt][jj] * scale : -3.0e38f;
        mx = fmaxf(mx, s[jt][jj]);
      }
    }
  }
  mx = fmaxf(mx, __shfl_xor(mx, 16, 64));
  mx = fmaxf(mx, __shfl_xor(mx, 32, 64));
  float l = 0.f;
#pragma unroll
  for (int jt = 0; jt < 16; ++jt) {
#pragma unroll
    for (int jj = 0; jj < 4; ++jj) {
      const float p = __expf(s[jt][jj] - mx);
      s[jt][jj] = p;
      l += p;
    }
  }
  l += __shfl_xor(l, 16, 64);
  l += __shfl_xor(l, 32, 64);

  f32x4 oa[2];
  oa[0] = (f32x4){0.f, 0.f, 0.f, 0.f};
  oa[1] = (f32x4){0.f, 0.f, 0.f, 0.f};
#pragma unroll
  for (int p2 = 0; p2 < 8; ++p2) {
    if (p2 * 2 < njt) {
      bf16x8 pa;
      pa[0] = (short)f2bf(s[p2 * 2][0]);     pa[1] = (short)f2bf(s[p2 * 2][1]);
      pa[2] = (short)f2bf(s[p2 * 2][2]);     pa[3] = (short)f2bf(s[p2 * 2][3]);
      pa[4] = (short)f2bf(s[p2 * 2 + 1][0]); pa[5] = (short)f2bf(s[p2 * 2 + 1][1]);
      pa[6] = (short)f2bf(s[p2 * 2 + 1][2]); pa[7] = (short)f2bf(s[p2 * 2 + 1][3]);
      const int jb0 = min(jbase + p2 * 32 + fs * 4, 2044);
      const int jb1 = min(jbase + p2 * 32 + 16 + fs * 4, 2044);
#pragma unroll
      for (int nt = 0; nt < 2; ++nt) {
        const short* vrow = vtg + (size_t)(w * 32 + nt * 16 + fr) * 2048;
        const short4 v0 = *(const short4*)(vrow + jb0);
        const short4 v1 = *(const short4*)(vrow + jb1);
        bf16x8 vf;
        vf[0] = v0.x; vf[1] = v0.y; vf[2] = v0.z; vf[3] = v0.w;
        vf[4] = v1.x; vf[5] = v1.y; vf[6] = v1.z; vf[7] = v1.w;
        oa[nt] = __builtin_amdgcn_mfma_f32_16x16x32_bf16(pa, vf, oa[nt], 0, 0, 0);
      }
    }
  }

#pragma unroll
  for (int jj = 0; jj < 4; ++jj) {
    const float lq = __shfl(l, fs * 4 + jj, 64);
    const float inv = (lq > 0.f) ? (1.f / lq) : 0.f;
    const int q = fs * 4 + jj;
    Ot[w][q][fr] = (short)f2bf(oa[0][jj] * inv);
    Ot[w][q][16 + fr] = (short)f2bf(oa[1][jj] * inv);
  }
  __syncthreads();

  // out-proj, full K=256: wave w owns col-tiles 2w, 2w+1
  f32x4 acc2[2];
  acc2[0] = (f32x4){0.f, 0.f, 0.f, 0.f};
  acc2[1] = (f32x4){0.f, 0.f, 0.f, 0.f};
#pragma unroll
  for (int ks = 0; ks < 8; ++ks) {
    const bf16x8 afrag = *(const bf16x8*)&Ot[ks][fr][fs * 8];
#pragma unroll
    for (int nt2 = 0; nt2 < 2; ++nt2) {
      const int col_row = (w * 2 + nt2) * 16 + fr;
      const bf16x8 bfrag =
          *(const bf16x8*)(out_t + (size_t)col_row * 256 + ks * 32 + fs * 8);
      acc2[nt2] = __builtin_amdgcn_mfma_f32_16x16x32_bf16(afrag, bfrag, acc2[nt2], 0, 0, 0);
    }
  }

  float d[2][4], ps[4], pq[4];
#pragma unroll
  for (int jj = 0; jj < 4; ++jj) {
    const int node = q0 + fs * 4 + jj;
    const int noder = min(node, 2047);
#pragma unroll
    for (int nt2 = 0; nt2 < 2; ++nt2) {
      const int col = w * 32 + nt2 * 16 + fr;
      d[nt2][jj] = acc2[nt2][jj] + outb[col] + h[(size_t)noder * 256 + col];
    }
    ps[jj] = d[0][jj] + d[1][jj];
    pq[jj] = d[0][jj] * d[0][jj] + d[1][jj] * d[1][jj];
#pragma unroll
    for (int m = 1; m <= 8; m <<= 1) {
      ps[jj] += __shfl_xor(ps[jj], m, 64);
      pq[jj] += __shfl_xor(pq[jj], m, 64);
    }
  }
  if (fr == 0) {
#pragma unroll
    for (int jj = 0; jj < 4; ++jj) {
      redS[w][fs * 4 + jj] = ps[jj];
      redQ[w][fs * 4 + jj] = pq[jj];
    }
  }
  __syncthreads();

#pragma unroll
  for (int jj = 0; jj < 4; ++jj) {
    const int row = fs * 4 + jj;
    float S = 0.f, Q = 0.f;
#pragma unroll
    for (int ww = 0; ww < 8; ++ww) { S += redS[ww][row]; Q += redQ[ww][row]; }
    const float mean = S * (1.f / 256.f);
    const float var = Q * (1.f / 256.f) - mean * mean;
    const float rs = rsqrtf(var + 1e-5f);
    const int node = q0 + row;
    if (active && node < je) {
#pragma unroll
      for (int nt2 = 0; nt2 < 2; ++nt2) {
        const int col = w * 32 + nt2 * 16 + fr;
        const float o = (d[nt2][jj] - mean) * rs * lns[col] + lnb[col];
        h[(size_t)node * 256 + col] = o;
        hb[(size_t)node * 256 + col] = (short)f2bf(o);
      }
    }
  }
}

// ---------------- fused residual + P-partial sum + LayerNorm; writes f32 + bf16 ----------------
template <int P>
__global__ __launch_bounds__(256) void ln_kernel(
    const float* __restrict__ base, const float* __restrict__ delta,
    const float* __restrict__ s, const float* __restrict__ b,
    float* __restrict__ outf, short* __restrict__ outb) {
  const int row = blockIdx.x * 4 + (threadIdx.x >> 6);
  const int lane = threadIdx.x & 63;
  float4 v = *(const float4*)(base + (size_t)row * 256 + lane * 4);
#pragma unroll
  for (int p = 0; p < P; ++p) {
    const float4 xb = *(const float4*)(delta + (size_t)(p * 2048 + row) * 256 + lane * 4);
    v.x += xb.x; v.y += xb.y; v.z += xb.z; v.w += xb.w;
  }
  float sum = wave_sum64(v.x + v.y + v.z + v.w);
  const float mean = sum * (1.f / 256.f);
  float4 d = make_float4(v.x - mean, v.y - mean, v.z - mean, v.w - mean);
  float sq = wave_sum64(d.x * d.x + d.y * d.y + d.z * d.z + d.w * d.w);
  const float rs = rsqrtf(sq * (1.f / 256.f) + 1e-5f);
  const float4 sv = *(const float4*)(s + lane * 4);
  const float4 bv = *(const float4*)(b + lane * 4);
  float4 o = make_float4(d.x * rs * sv.x + bv.x, d.y * rs * sv.y + bv.y,
                         d.z * rs * sv.z + bv.z, d.w * rs * sv.w + bv.w);
  *(float4*)(outf + (size_t)row * 256 + lane * 4) = o;
  short4 ob;
  ob.x = (short)f2bf(o.x); ob.y = (short)f2bf(o.y);
  ob.z = (short)f2bf(o.z); ob.w = (short)f2bf(o.w);
  *(short4*)(outb + (size_t)row * 256 + lane * 4) = ob;
}

// ---------------- heads: lat (blocks 0..31) + beta (blocks 32..159), one dispatch ----------------
__global__ __launch_bounds__(256) void heads_kernel(
    const short* __restrict__ A, const short* __restrict__ lat_t,
    const float* __restrict__ lat_b, float* __restrict__ lat_out,
    const short* __restrict__ b1_t, const float* __restrict__ b1b,
    const float* __restrict__ w2, const float* __restrict__ b2b,
    float* __restrict__ beta) {
  __shared__ short smem[64 * 128 * 2];
  const int t = threadIdx.x;
  const int lane = t & 63, w = t >> 6;
  const int fr = lane & 15, fs = lane >> 4;

  if (blockIdx.x < 32) {  // ---- lat tile: GEMM (N=32, K=256) + row-normalize ----
    short* As = smem;
    short* Bs = smem + 64 * 128;
    const int bm = blockIdx.x;
    const int srow = t >> 2, sq = t & 3;
    const int rx = srow & 7;
    f32x4 acc[2];
    acc[0] = (f32x4){0.f, 0.f, 0.f, 0.f};
    acc[1] = (f32x4){0.f, 0.f, 0.f, 0.f};
    const short* ap = A + (size_t)(bm * 64 + srow) * 256;
    const short* bp = lat_t + (size_t)srow * 256;
    const int ar = w * 16 + fr;
    for (int k0 = 0; k0 < 256; k0 += 128) {
      bf16x8 av[4], bv[4];
#pragma unroll
      for (int i = 0; i < 4; ++i) av[i] = *(const bf16x8*)(ap + k0 + (sq * 4 + i) * 8);
      if (srow < 32) {
#pragma unroll
        for (int i = 0; i < 4; ++i) bv[i] = *(const bf16x8*)(bp + k0 + (sq * 4 + i) * 8);
      } else {
#pragma unroll
        for (int i = 0; i < 4; ++i) bv[i] = (bf16x8){0, 0, 0, 0, 0, 0, 0, 0};
      }
      __syncthreads();
#pragma unroll
      for (int i = 0; i < 4; ++i) {
        const int s = sq * 4 + i;
        *(bf16x8*)(As + srow * 128 + ((s ^ rx) * 8)) = av[i];
        *(bf16x8*)(Bs + srow * 128 + ((s ^ rx) * 8)) = bv[i];
      }
      __syncthreads();
#pragma unroll
      for (int ks = 0; ks < 4; ++ks) {
        const int u = ks * 4 + fs;
        bf16x8 a0 = *(const bf16x8*)(As + ar * 128 + ((u ^ (ar & 7)) * 8));
        bf16x8 b0 = *(const bf16x8*)(Bs + fr * 128 + ((u ^ (fr & 7)) * 8));
        bf16x8 b1 = *(const bf16x8*)(Bs + (16 + fr) * 128 + ((u ^ ((16 + fr) & 7)) * 8));
        acc[0] = __builtin_amdgcn_mfma_f32_16x16x32_bf16(a0, b0, acc[0], 0, 0, 0);
        acc[1] = __builtin_amdgcn_mfma_f32_16x16x32_bf16(a0, b1, acc[1], 0, 0, 0);
      }
    }
    const float b0v = lat_b[fr], b1v = lat_b[16 + fr];
#pragma unroll
    for (int j = 0; j < 4; ++j) {
      const int row = bm * 64 + w * 16 + fs * 4 + j;
      float v0 = acc[0][j] + b0v;
      float v1 = acc[1][j] + b1v;
      float ss = v0 * v0 + v1 * v1;
      ss += __shfl_xor(ss, 1, 64);
      ss += __shfl_xor(ss, 2, 64);
      ss += __shfl_xor(ss, 4, 64);
      ss += __shfl_xor(ss, 8, 64);
      const float inv = 5.656854249492381f / fmaxf(sqrtf(ss), 1e-12f);
      lat_out[(size_t)row * 32 + fr] = v0 * inv;
      lat_out[(size_t)row * 32 + 16 + fr] = v1 * inv;
    }
  } else {  // ---- beta: sigmoid(relu(h@W1+b1)@w2+b2), 16 rows per block ----
    float* red = (float*)smem;
    const int rb = (blockIdx.x - 32) * 16;
    f32x4 acc[2];
    acc[0] = (f32x4){0.f, 0.f, 0.f, 0.f};
    acc[1] = (f32x4){0.f, 0.f, 0.f, 0.f};
    const short* ap = A + (size_t)(rb + fr) * 256;
    const short* bp = b1_t + (size_t)(w * 32 + fr) * 256;
    for (int k0 = 0; k0 < 256; k0 += 32) {
      const bf16x8 af = *(const bf16x8*)(ap + k0 + fs * 8);
#pragma unroll
      for (int n = 0; n < 2; ++n) {
        const bf16x8 bf = *(const bf16x8*)(bp + (size_t)n * 16 * 256 + k0 + fs * 8);
        acc[n] = __builtin_amdgcn_mfma_f32_16x16x32_bf16(af, bf, acc[n], 0, 0, 0);
      }
    }
    const int c0 = w * 32 + fr, c1 = c0 + 16;
    const float b0 = b1b[c0], b1 = b1b[c1];
    const float w0 = w2[c0], w1 = w2[c1];
    float part[4];
#pragma unroll
    for (int j = 0; j < 4; ++j) {
      const float d0 = fmaxf(acc[0][j] + b0, 0.f);
      const float d1 = fmaxf(acc[1][j] + b1, 0.f);
      part[j] = d0 * w0 + d1 * w1;
#pragma unroll
      for (int m = 1; m <= 8; m <<= 1) part[j] += __shfl_xor(part[j], m, 64);
    }
    if (fr == 0) {
#pragma unroll
      for (int j = 0; j < 4; ++j) red[w * 16 + fs * 4 + j] = part[j];
    }
    __syncthreads();
    if (t < 16) {
      const float S = red[t] + red[16 + t] + red[32 + t] + red[48 + t] + b2b[0];
      float sgm = 1.f / (1.f + __expf(-S));
      sgm = fminf(fmaxf(sgm, 1e-6f), 1.f - 1e-6f);
      beta[rb + t] = sgm;
    }
  }
}

// ---------------- launch ----------------
extern "C" void kernel_launch(void* const* d_in, const int* in_sizes, int n_in,
                              void* d_out, int out_size, void* d_ws, size_t ws_size,
                              hipStream_t stream) {
  const int N = 2048, D = 256, FF = 1024, L = 4;

  const float* x     = (const float*)d_in[0];
  const int*   batch = (const int*)d_in[2];
  const float* Wi    = (const float*)d_in[3];
  const float* bi    = (const float*)d_in[4];
  const float* qkv_w = (const float*)d_in[5];
  const float* qkv_b = (const float*)d_in[6];
  const float* out_w = (const float*)d_in[7];
  const float* out_b = (const float*)d_in[8];
  const float* ff1_w = (const float*)d_in[9];
  const float* ff1_b = (const float*)d_in[10];
  const float* ff2_w = (const float*)d_in[11];
  const float* ff2_b = (const float*)d_in[12];
  const float* ln1_s = (const float*)d_in[13];
  const float* ln1_b = (const float*)d_in[14];
  const float* ln2_s = (const float*)d_in[15];
  const float* ln2_b = (const float*)d_in[16];
  const float* lat_w = (const float*)d_in[17];
  const float* lat_b = (const float*)d_in[18];
  const float* b1_w  = (const float*)d_in[19];
  const float* b1_b  = (const float*)d_in[20];
  const float* b2_w  = (const float*)d_in[21];
  const float* b2_b  = (const float*)d_in[22];

  float* ws = (float*)d_ws;
  float* h      = ws;                              // N*D f32
  float* tmp    = h + (size_t)N * D;               // 4*N*D f32 (ff2 split-K partials)
  int*  starts  = (int*)(tmp + (size_t)4 * N * D); // 32 ints
  int*  meta    = starts + 32;                     // 448 ints
  short* hb     = (short*)(meta + 448);            // N*D bf16
  short* qkvb   = hb + (size_t)N * D;              // N*3D bf16 (V cols unused)
  short* ffb    = qkvb + (size_t)N * 3 * D;        // N*FF bf16
  short* vtg    = ffb + (size_t)N * FF;            // 256*2048 bf16 (V^T per layer)
  short* qkv_t  = vtg + (size_t)256 * 2048;
  short* out_t  = qkv_t + (size_t)L * 768 * 256;
  short* ff1_t  = out_t + (size_t)L * 256 * 256;
  short* ff2_t  = ff1_t + (size_t)L * 1024 * 256;
  short* b1_t   = ff2_t + (size_t)L * 256 * 1024;
  short* lat_t  = b1_t + (size_t)128 * 256;

  float* beta_out = (float*)d_out;
  float* lat_out  = beta_out + N;

  pack_inproj<<<3113 + 2048, 256, 0, stream>>>(
      qkv_w, out_w, ff1_w, ff2_w, b1_w, lat_w,
      qkv_t, out_t, ff1_t, ff2_t, b1_t, lat_t,
      batch, starts, meta, x, Wi, bi, h, hb);

  for (int l = 0; l < L; ++l) {
    // qkv = h @ qkv_w + b -> bf16 Q,K (+ coalesced V^T)
    gemm_bf16<0, 0, 1><<<dim3(12, 32, 1), 256, 0, stream>>>(
        hb, qkv_t + (size_t)l * 768 * 256, qkv_b + (size_t)l * 768,
        nullptr, qkvb, vtg, N, 768, 256, 256);
    // attention + out-proj + residual + LN1
    attn_fused<<<144, 512, 0, stream>>>(
        qkvb, vtg, meta, out_t + (size_t)l * 256 * 256, out_b + (size_t)l * 256,
        ln1_s + (size_t)l * D, ln1_b + (size_t)l * D, h, hb);
    // ff1 = relu(h @ ff1_w + b) -> bf16
    gemm_bf16<1, 0, 0><<<dim3(16, 32, 1), 256, 0, stream>>>(
        hb, ff1_t + (size_t)l * FF * 256, ff1_b + (size_t)l * FF,
        nullptr, ffb, nullptr, N, FF, 256, 256);
    // ff2 split-K=4 -> f32 partials
    gemm_bf16<0, 4, 0><<<dim3(4, 32, 4), 256, 0, stream>>>(
        ffb, ff2_t + (size_t)l * 256 * FF, ff2_b + (size_t)l * 256,
        tmp, nullptr, nullptr, N, 256, 1024, 256);
    // residual + 4 partials + LN2
    ln_kernel<4><<<N / 4, 256, 0, stream>>>(
        h, tmp, ln2_s + (size_t)l * D, ln2_b + (size_t)l * D, h, hb);
  }

  heads_kernel<<<160, 256, 0, stream>>>(hb, lat_t, lat_b, lat_out,
                                        b1_t, b1_b, b2_w, b2_b, beta_out);
}

// Round 20
// 182.320 us; speedup vs baseline: 1.5623x; 1.0094x over previous
//
#include <hip/hip_runtime.h>
#include <hip/hip_bf16.h>

typedef __attribute__((ext_vector_type(8))) short bf16x8;
typedef __attribute__((ext_vector_type(4))) float f32x4;

// ---------------- helpers ----------------
__device__ inline float wave_sum64(float v) {
#pragma unroll
  for (int m = 32; m >= 1; m >>= 1) v += __shfl_xor(v, m, 64);
  return v;
}
__device__ inline ushort f2bf(float f) {  // RNE float->bf16
  uint u = __float_as_uint(f);
  return (ushort)((u + 0x7FFFu + ((u >> 16) & 1u)) >> 16);
}
// direct global->LDS DMA, 16B per lane; lds base must be wave-uniform
__device__ inline void gload16(const short* g, short* lds) {
  __builtin_amdgcn_global_load_lds(
      (const __attribute__((address_space(1))) void*)g,
      (__attribute__((address_space(3))) void*)lds, 16, 0, 0);
}

// ---------------- weight pack + starts/meta + input projection (one dispatch) ----------------
__global__ __launch_bounds__(256) void pack_inproj(
    const float* __restrict__ qkv_w, const float* __restrict__ out_w,
    const float* __restrict__ ff1_w, const float* __restrict__ ff2_w,
    const float* __restrict__ b1_w, const float* __restrict__ lat_w,
    short* __restrict__ qkv_t, short* __restrict__ out_t,
    short* __restrict__ ff1_t, short* __restrict__ ff2_t,
    short* __restrict__ b1_t, short* __restrict__ lat_t,
    const int* __restrict__ batch, int* __restrict__ starts, int* __restrict__ meta,
    const float* __restrict__ x, const float* __restrict__ Wi,
    const float* __restrict__ bi, float* __restrict__ h, short* __restrict__ hb) {
  int t = blockIdx.x;
  __shared__ float tile[32][33];

  if (t >= 3113) {  // input projection: one row per block
    const int row = t - 3113;
    const int j = threadIdx.x;
    float* xs = &tile[0][0];
    if (j < 16) xs[j] = x[(size_t)row * 16 + j];
    __syncthreads();
    float acc = bi[j];
#pragma unroll
    for (int k = 0; k < 16; ++k) acc += xs[k] * Wi[k * 256 + j];
    h[(size_t)row * 256 + j] = acc;
    hb[(size_t)row * 256 + j] = (short)f2bf(acc);
    return;
  }
  if (t == 3112) {  // graph boundaries + graph-aligned 16-row tile list
    for (int i = threadIdx.x; i < 2048; i += 256) {
      int b = batch[i];
      if (i == 0) {
        for (int g = 0; g <= b; ++g) starts[g] = 0;
      } else {
        int bp = batch[i - 1];
        for (int g = bp + 1; g <= b; ++g) starts[g] = i;
      }
      if (i == 2047) {
        for (int g = b + 1; g <= 16; ++g) starts[g] = 2048;
      }
    }
    __syncthreads();
    if (threadIdx.x == 0) {
      int nt = 0;
      for (int g = 0; g < 16; ++g) {
        const int js = starts[g], je = starts[g + 1];
        for (int q0 = js; q0 < je; q0 += 16) {
          meta[1 + nt * 3] = q0;
          meta[2 + nt * 3] = js;
          meta[3 + nt * 3] = je;
          ++nt;
        }
      }
      meta[0] = nt;
    }
    return;
  }
  const float* src;
  short* dst;
  int Kd, Nd, rem;
  if (t < 768) {
    int l = t / 192; rem = t % 192; Kd = 256; Nd = 768;
    src = qkv_w + (size_t)l * Kd * Nd; dst = qkv_t + (size_t)l * Nd * Kd;
  } else if (t < 1024) {
    t -= 768; int l = t / 64; rem = t % 64; Kd = 256; Nd = 256;
    src = out_w + (size_t)l * Kd * Nd; dst = out_t + (size_t)l * Nd * Kd;
  } else if (t < 2048) {
    t -= 1024; int l = t / 256; rem = t % 256; Kd = 256; Nd = 1024;
    src = ff1_w + (size_t)l * Kd * Nd; dst = ff1_t + (size_t)l * Nd * Kd;
  } else if (t < 3072) {
    t -= 2048; int l = t / 256; rem = t % 256; Kd = 1024; Nd = 256;
    src = ff2_w + (size_t)l * Kd * Nd; dst = ff2_t + (size_t)l * Nd * Kd;
  } else if (t < 3104) {
    rem = t - 3072; Kd = 256; Nd = 128; src = b1_w; dst = b1_t;
  } else {
    rem = t - 3104; Kd = 256; Nd = 32; src = lat_w; dst = lat_t;
  }
  const int ntn = Nd / 32;
  const int kt = rem / ntn, nt = rem % ntn;
  const int tx = threadIdx.x & 31, ty = threadIdx.x >> 5;
#pragma unroll
  for (int r = 0; r < 4; ++r) {
    int k = kt * 32 + ty + r * 8;
    tile[ty + r * 8][tx] = src[(size_t)k * Nd + nt * 32 + tx];
  }
  __syncthreads();
#pragma unroll
  for (int r = 0; r < 4; ++r) {
    int n = nt * 32 + ty + r * 8;
    dst[(size_t)n * Kd + kt * 32 + tx] = (short)f2bf(tile[tx][ty + r * 8]);
  }
}

// ---------------- MFMA bf16 GEMM, BK=128; staging via global_load_lds (16B) ----------------
// P=0: bf16 out; P>0: split-K (blockIdx.z) f32 partials at Cf + z*M*N (bias z==0).
// VT=1 (qkv): V cols (bn>=8) go ONLY to V^T [256][2048] via LDS transpose.
// LDS layout: linear DMA dest + inverse-swizzled global source; reads keep the
// (u ^ (row&7)) swizzle -> bit-identical math vs reg-staged r18. N % 64 == 0.
template <int ACT, int P, int VT>
__global__ __launch_bounds__(256) void gemm_bf16(
    const short* __restrict__ A, const short* __restrict__ Bt,
    const float* __restrict__ bias, float* __restrict__ Cf, short* __restrict__ Cb,
    short* __restrict__ vtg, int M, int N, int K, int kpb) {
  __shared__ short As[64 * 128];
  __shared__ short Bs[64 * 128];

  const int t = threadIdx.x;
  const int bm = blockIdx.y, bn = blockIdx.x, bz = blockIdx.z;
  const int lane = t & 63, wid = t >> 6;
  const int wr = wid >> 1, wc = wid & 1;
  const int fr = lane & 15, fs = lane >> 4;

  f32x4 acc[2][2];
#pragma unroll
  for (int m = 0; m < 2; ++m)
#pragma unroll
    for (int n = 0; n < 2; ++n) acc[m][n] = (f32x4){0.f, 0.f, 0.f, 0.f};

  const int kbase = bz * kpb;
  const short* Ag = A + (size_t)bm * 64 * K + kbase;   // tile row 0
  const short* Bg = Bt + (size_t)bn * 64 * K + kbase;
  const int ri = lane >> 4;   // local row within a 4-row DMA chunk
  const int sl = lane & 15;   // linear 16B slot within row
  const int ar0 = wr * 32 + fr, ar1 = ar0 + 16;
  const int bc0 = wc * 32 + fr, bc1 = bc0 + 16;

  for (int k0 = 0; k0 < kpb; k0 += 128) {
    __syncthreads();  // prior-tile LDS reads done before DMA overwrite
#pragma unroll
    for (int c = 0; c < 4; ++c) {
      const int r0 = wid * 16 + c * 4;       // wave-uniform row base
      const int r = r0 + ri;                 // per-lane row
      const int sa = sl ^ (r & 7);           // inverse swizzle on source
      gload16(Ag + (size_t)r * K + k0 + sa * 8, As + r0 * 128);
      gload16(Bg + (size_t)r * K + k0 + sa * 8, Bs + r0 * 128);
    }
    __syncthreads();  // drains vmcnt: DMA complete before reads
#pragma unroll
    for (int ks = 0; ks < 4; ++ks) {
      const int u = ks * 4 + fs;
      bf16x8 a0 = *(const bf16x8*)(As + ar0 * 128 + ((u ^ (ar0 & 7)) * 8));
      bf16x8 a1 = *(const bf16x8*)(As + ar1 * 128 + ((u ^ (ar1 & 7)) * 8));
      bf16x8 b0 = *(const bf16x8*)(Bs + bc0 * 128 + ((u ^ (bc0 & 7)) * 8));
      bf16x8 b1 = *(const bf16x8*)(Bs + bc1 * 128 + ((u ^ (bc1 & 7)) * 8));
      acc[0][0] = __builtin_amdgcn_mfma_f32_16x16x32_bf16(a0, b0, acc[0][0], 0, 0, 0);
      acc[0][1] = __builtin_amdgcn_mfma_f32_16x16x32_bf16(a0, b1, acc[0][1], 0, 0, 0);
      acc[1][0] = __builtin_amdgcn_mfma_f32_16x16x32_bf16(a1, b0, acc[1][0], 0, 0, 0);
      acc[1][1] = __builtin_amdgcn_mfma_f32_16x16x32_bf16(a1, b1, acc[1][1], 0, 0, 0);
    }
  }

  if (P == 0) {
    if (!(VT && bn >= 8)) {
#pragma unroll
      for (int n = 0; n < 2; ++n) {
        const int col = bn * 64 + wc * 32 + n * 16 + fr;
        const float bvv = bias[col];
#pragma unroll
        for (int m = 0; m < 2; ++m) {
          const int rbase = bm * 64 + wr * 32 + m * 16 + fs * 4;
#pragma unroll
          for (int j = 0; j < 4; ++j) {
            float v = acc[m][n][j] + bvv;
            if (ACT == 1) v = fmaxf(v, 0.f);
            Cb[(size_t)(rbase + j) * N + col] = (short)f2bf(v);
          }
        }
      }
    }
    if (VT && bn >= 8) {  // coalesced V^T epilogue for qkv cols [512,768)
      short* tr = As;  // reuse LDS: [64 cols][68 rows]
      __syncthreads();
#pragma unroll
      for (int n = 0; n < 2; ++n) {
        const int c = wc * 32 + n * 16 + fr;
        const float bvv = bias[bn * 64 + c];
#pragma unroll
        for (int m = 0; m < 2; ++m)
#pragma unroll
          for (int j = 0; j < 4; ++j) {
            const int r = wr * 32 + m * 16 + fs * 4 + j;
            tr[c * 68 + r] = (short)f2bf(acc[m][n][j] + bvv);
          }
      }
      __syncthreads();
      const int tx = t & 63, ty = t >> 6;
      const int d0 = bn * 64 - 512, rb = bm * 64;
#pragma unroll
      for (int r = 0; r < 16; ++r) {
        const int d = ty * 16 + r;
        vtg[(size_t)(d0 + d) * 2048 + rb + tx] = tr[d * 68 + tx];
      }
    }
  } else {
    // split-K f32 partial store (no sync; consumer ln_kernel sums)
#pragma unroll
    for (int n = 0; n < 2; ++n) {
      const int col = bn * 64 + wc * 32 + n * 16 + fr;
      const float bvv = (bz == 0) ? bias[col] : 0.f;
#pragma unroll
      for (int m = 0; m < 2; ++m) {
        const int rbase = bm * 64 + wr * 32 + m * 16 + fs * 4;
#pragma unroll
        for (int j = 0; j < 4; ++j) {
          Cf[(size_t)(bz * M + rbase + j) * N + col] = acc[m][n][j] + bvv;
        }
      }
    }
  }
}

// ---------------- attention + full out-proj + residual + LN1, one block per q-tile ----------------
// 512 threads = 8 waves; wave w = head w (r15-proven). O -> Ot LDS; barrier; each wave
// does 2 col-tiles of out-proj at full K=256; block applies residual + LN via LDS reduce.
// Inactive blocks (tile >= meta[0]) exit uniformly before any barrier.
__global__ __launch_bounds__(512) void attn_fused(
    const short* __restrict__ qkv, const short* __restrict__ vtg,
    const int* __restrict__ meta, const short* __restrict__ out_t,
    const float* __restrict__ outb, const float* __restrict__ lns,
    const float* __restrict__ lnb, float* __restrict__ h, short* __restrict__ hb) {
  __shared__ short Ot[8][16][40];
  __shared__ float redS[8][16], redQ[8][16];
  const int w = threadIdx.x >> 6;  // wave = head
  const int tile = blockIdx.x;
  if (tile >= meta[0]) return;     // uniform per block; before any __syncthreads
  const int lane = threadIdx.x & 63;
  const int fr = lane & 15, fs = lane >> 4;
  const int q0 = meta[1 + tile * 3];
  const int js = meta[2 + tile * 3];
  const int je = meta[3 + tile * 3];
  const int jbase = js & ~15;
  const int njt = (je - jbase + 15) >> 4;  // <=16
  const float scale = 0.17677669529663687f;  // 1/sqrt(32)

  const int qrow = min(q0 + fr, 2047);
  const bf16x8 qf = *(const bf16x8*)(qkv + (size_t)qrow * 768 + w * 32 + fs * 8);
  const int jeq = (q0 + fr < je) ? je : 0;

  f32x4 s[16];
#pragma unroll
  for (int jt = 0; jt < 16; ++jt)
    s[jt] = (f32x4){-3.0e38f, -3.0e38f, -3.0e38f, -3.0e38f};

#pragma unroll
  for (int jt = 0; jt < 16; ++jt) {
    if (jt < njt) {
      const int krow = min(jbase + jt * 16 + fr, 2047);
      const bf16x8 kf = *(const bf16x8*)(qkv + (size_t)krow * 768 + 256 + w * 32 + fs * 8);
      s[jt] = __builtin_amdgcn_mfma_f32_16x16x32_bf16(
          kf, qf, (f32x4){0.f, 0.f, 0.f, 0.f}, 0, 0, 0);
    }
  }
  float mx = -3.0e38f;
#pragma unroll
  for (int jt = 0; jt < 16; ++jt) {
    if (jt < njt) {
#pragma unroll
      for (int jj = 0; jj < 4; ++jj) {
        const int j = jbase + jt * 16 + fs * 4 + jj;
        const bool valid = (j >= js) && (j < jeq);
        s[jt][jj] = valid ? s[jt][jj] * scale : -3.0e38f;
        mx = fmaxf(mx, s[jt][jj]);
      }
    }
  }
  mx = fmaxf(mx, __shfl_xor(mx, 16, 64));
  mx = fmaxf(mx, __shfl_xor(mx, 32, 64));
  float l = 0.f;
#pragma unroll
  for (int jt = 0; jt < 16; ++jt) {
#pragma unroll
    for (int jj = 0; jj < 4; ++jj) {
      const float p = __expf(s[jt][jj] - mx);
      s[jt][jj] = p;
      l += p;
    }
  }
  l += __shfl_xor(l, 16, 64);
  l += __shfl_xor(l, 32, 64);

  f32x4 oa[2];
  oa[0] = (f32x4){0.f, 0.f, 0.f, 0.f};
  oa[1] = (f32x4){0.f, 0.f, 0.f, 0.f};
#pragma unroll
  for (int p2 = 0; p2 < 8; ++p2) {
    if (p2 * 2 < njt) {
      bf16x8 pa;
      pa[0] = (short)f2bf(s[p2 * 2][0]);     pa[1] = (short)f2bf(s[p2 * 2][1]);
      pa[2] = (short)f2bf(s[p2 * 2][2]);     pa[3] = (short)f2bf(s[p2 * 2][3]);
      pa[4] = (short)f2bf(s[p2 * 2 + 1][0]); pa[5] = (short)f2bf(s[p2 * 2 + 1][1]);
      pa[6] = (short)f2bf(s[p2 * 2 + 1][2]); pa[7] = (short)f2bf(s[p2 * 2 + 1][3]);
      const int jb0 = min(jbase + p2 * 32 + fs * 4, 2044);
      const int jb1 = min(jbase + p2 * 32 + 16 + fs * 4, 2044);
#pragma unroll
      for (int nt = 0; nt < 2; ++nt) {
        const short* vrow = vtg + (size_t)(w * 32 + nt * 16 + fr) * 2048;
        const short4 v0 = *(const short4*)(vrow + jb0);
        const short4 v1 = *(const short4*)(vrow + jb1);
        bf16x8 vf;
        vf[0] = v0.x; vf[1] = v0.y; vf[2] = v0.z; vf[3] = v0.w;
        vf[4] = v1.x; vf[5] = v1.y; vf[6] = v1.z; vf[7] = v1.w;
        oa[nt] = __builtin_amdgcn_mfma_f32_16x16x32_bf16(pa, vf, oa[nt], 0, 0, 0);
      }
    }
  }

#pragma unroll
  for (int jj = 0; jj < 4; ++jj) {
    const float lq = __shfl(l, fs * 4 + jj, 64);
    const float inv = (lq > 0.f) ? (1.f / lq) : 0.f;
    const int q = fs * 4 + jj;
    Ot[w][q][fr] = (short)f2bf(oa[0][jj] * inv);
    Ot[w][q][16 + fr] = (short)f2bf(oa[1][jj] * inv);
  }
  __syncthreads();

  // out-proj, full K=256: wave w owns col-tiles 2w, 2w+1
  f32x4 acc2[2];
  acc2[0] = (f32x4){0.f, 0.f, 0.f, 0.f};
  acc2[1] = (f32x4){0.f, 0.f, 0.f, 0.f};
#pragma unroll
  for (int ks = 0; ks < 8; ++ks) {
    const bf16x8 afrag = *(const bf16x8*)&Ot[ks][fr][fs * 8];
#pragma unroll
    for (int nt2 = 0; nt2 < 2; ++nt2) {
      const int col_row = (w * 2 + nt2) * 16 + fr;
      const bf16x8 bfrag =
          *(const bf16x8*)(out_t + (size_t)col_row * 256 + ks * 32 + fs * 8);
      acc2[nt2] = __builtin_amdgcn_mfma_f32_16x16x32_bf16(afrag, bfrag, acc2[nt2], 0, 0, 0);
    }
  }

  float d[2][4], ps[4], pq[4];
#pragma unroll
  for (int jj = 0; jj < 4; ++jj) {
    const int node = q0 + fs * 4 + jj;
    const int noder = min(node, 2047);
#pragma unroll
    for (int nt2 = 0; nt2 < 2; ++nt2) {
      const int col = w * 32 + nt2 * 16 + fr;
      d[nt2][jj] = acc2[nt2][jj] + outb[col] + h[(size_t)noder * 256 + col];
    }
    ps[jj] = d[0][jj] + d[1][jj];
    pq[jj] = d[0][jj] * d[0][jj] + d[1][jj] * d[1][jj];
#pragma unroll
    for (int m = 1; m <= 8; m <<= 1) {
      ps[jj] += __shfl_xor(ps[jj], m, 64);
      pq[jj] += __shfl_xor(pq[jj], m, 64);
    }
  }
  if (fr == 0) {
#pragma unroll
    for (int jj = 0; jj < 4; ++jj) {
      redS[w][fs * 4 + jj] = ps[jj];
      redQ[w][fs * 4 + jj] = pq[jj];
    }
  }
  __syncthreads();

#pragma unroll
  for (int jj = 0; jj < 4; ++jj) {
    const int row = fs * 4 + jj;
    float S = 0.f, Q = 0.f;
#pragma unroll
    for (int ww = 0; ww < 8; ++ww) { S += redS[ww][row]; Q += redQ[ww][row]; }
    const float mean = S * (1.f / 256.f);
    const float var = Q * (1.f / 256.f) - mean * mean;
    const float rs = rsqrtf(var + 1e-5f);
    const int node = q0 + row;
    if (node < je) {
#pragma unroll
      for (int nt2 = 0; nt2 < 2; ++nt2) {
        const int col = w * 32 + nt2 * 16 + fr;
        const float o = (d[nt2][jj] - mean) * rs * lns[col] + lnb[col];
        h[(size_t)node * 256 + col] = o;
        hb[(size_t)node * 256 + col] = (short)f2bf(o);
      }
    }
  }
}

// ---------------- fused residual + P-partial sum + LayerNorm; writes f32 + bf16 ----------------
template <int P>
__global__ __launch_bounds__(256) void ln_kernel(
    const float* __restrict__ base, const float* __restrict__ delta,
    const float* __restrict__ s, const float* __restrict__ b,
    float* __restrict__ outf, short* __restrict__ outb) {
  const int row = blockIdx.x * 4 + (threadIdx.x >> 6);
  const int lane = threadIdx.x & 63;
  float4 v = *(const float4*)(base + (size_t)row * 256 + lane * 4);
#pragma unroll
  for (int p = 0; p < P; ++p) {
    const float4 xb = *(const float4*)(delta + (size_t)(p * 2048 + row) * 256 + lane * 4);
    v.x += xb.x; v.y += xb.y; v.z += xb.z; v.w += xb.w;
  }
  float sum = wave_sum64(v.x + v.y + v.z + v.w);
  const float mean = sum * (1.f / 256.f);
  float4 d = make_float4(v.x - mean, v.y - mean, v.z - mean, v.w - mean);
  float sq = wave_sum64(d.x * d.x + d.y * d.y + d.z * d.z + d.w * d.w);
  const float rs = rsqrtf(sq * (1.f / 256.f) + 1e-5f);
  const float4 sv = *(const float4*)(s + lane * 4);
  const float4 bv = *(const float4*)(b + lane * 4);
  float4 o = make_float4(d.x * rs * sv.x + bv.x, d.y * rs * sv.y + bv.y,
                         d.z * rs * sv.z + bv.z, d.w * rs * sv.w + bv.w);
  *(float4*)(outf + (size_t)row * 256 + lane * 4) = o;
  short4 ob;
  ob.x = (short)f2bf(o.x); ob.y = (short)f2bf(o.y);
  ob.z = (short)f2bf(o.z); ob.w = (short)f2bf(o.w);
  *(short4*)(outb + (size_t)row * 256 + lane * 4) = ob;
}

// ---------------- heads: lat (blocks 0..31) + beta (blocks 32..159), one dispatch ----------------
__global__ __launch_bounds__(256) void heads_kernel(
    const short* __restrict__ A, const short* __restrict__ lat_t,
    const float* __restrict__ lat_b, float* __restrict__ lat_out,
    const short* __restrict__ b1_t, const float* __restrict__ b1b,
    const float* __restrict__ w2, const float* __restrict__ b2b,
    float* __restrict__ beta) {
  __shared__ short smem[64 * 128 * 2];
  const int t = threadIdx.x;
  const int lane = t & 63, w = t >> 6;
  const int fr = lane & 15, fs = lane >> 4;

  if (blockIdx.x < 32) {  // ---- lat tile: GEMM (N=32, K=256) + row-normalize ----
    short* As = smem;
    short* Bs = smem + 64 * 128;
    const int bm = blockIdx.x;
    const int srow = t >> 2, sq = t & 3;
    const int rx = srow & 7;
    f32x4 acc[2];
    acc[0] = (f32x4){0.f, 0.f, 0.f, 0.f};
    acc[1] = (f32x4){0.f, 0.f, 0.f, 0.f};
    const short* ap = A + (size_t)(bm * 64 + srow) * 256;
    const short* bp = lat_t + (size_t)srow * 256;
    const int ar = w * 16 + fr;
    for (int k0 = 0; k0 < 256; k0 += 128) {
      bf16x8 av[4], bv[4];
#pragma unroll
      for (int i = 0; i < 4; ++i) av[i] = *(const bf16x8*)(ap + k0 + (sq * 4 + i) * 8);
      if (srow < 32) {
#pragma unroll
        for (int i = 0; i < 4; ++i) bv[i] = *(const bf16x8*)(bp + k0 + (sq * 4 + i) * 8);
      } else {
#pragma unroll
        for (int i = 0; i < 4; ++i) bv[i] = (bf16x8){0, 0, 0, 0, 0, 0, 0, 0};
      }
      __syncthreads();
#pragma unroll
      for (int i = 0; i < 4; ++i) {
        const int s = sq * 4 + i;
        *(bf16x8*)(As + srow * 128 + ((s ^ rx) * 8)) = av[i];
        *(bf16x8*)(Bs + srow * 128 + ((s ^ rx) * 8)) = bv[i];
      }
      __syncthreads();
#pragma unroll
      for (int ks = 0; ks < 4; ++ks) {
        const int u = ks * 4 + fs;
        bf16x8 a0 = *(const bf16x8*)(As + ar * 128 + ((u ^ (ar & 7)) * 8));
        bf16x8 b0 = *(const bf16x8*)(Bs + fr * 128 + ((u ^ (fr & 7)) * 8));
        bf16x8 b1 = *(const bf16x8*)(Bs + (16 + fr) * 128 + ((u ^ ((16 + fr) & 7)) * 8));
        acc[0] = __builtin_amdgcn_mfma_f32_16x16x32_bf16(a0, b0, acc[0], 0, 0, 0);
        acc[1] = __builtin_amdgcn_mfma_f32_16x16x32_bf16(a0, b1, acc[1], 0, 0, 0);
      }
    }
    const float b0v = lat_b[fr], b1v = lat_b[16 + fr];
#pragma unroll
    for (int j = 0; j < 4; ++j) {
      const int row = bm * 64 + w * 16 + fs * 4 + j;
      float v0 = acc[0][j] + b0v;
      float v1 = acc[1][j] + b1v;
      float ss = v0 * v0 + v1 * v1;
      ss += __shfl_xor(ss, 1, 64);
      ss += __shfl_xor(ss, 2, 64);
      ss += __shfl_xor(ss, 4, 64);
      ss += __shfl_xor(ss, 8, 64);
      const float inv = 5.656854249492381f / fmaxf(sqrtf(ss), 1e-12f);
      lat_out[(size_t)row * 32 + fr] = v0 * inv;
      lat_out[(size_t)row * 32 + 16 + fr] = v1 * inv;
    }
  } else {  // ---- beta: sigmoid(relu(h@W1+b1)@w2+b2), 16 rows per block ----
    float* red = (float*)smem;
    const int rb = (blockIdx.x - 32) * 16;
    f32x4 acc[2];
    acc[0] = (f32x4){0.f, 0.f, 0.f, 0.f};
    acc[1] = (f32x4){0.f, 0.f, 0.f, 0.f};
    const short* ap = A + (size_t)(rb + fr) * 256;
    const short* bp = b1_t + (size_t)(w * 32 + fr) * 256;
    for (int k0 = 0; k0 < 256; k0 += 32) {
      const bf16x8 af = *(const bf16x8*)(ap + k0 + fs * 8);
#pragma unroll
      for (int n = 0; n < 2; ++n) {
        const bf16x8 bf = *(const bf16x8*)(bp + (size_t)n * 16 * 256 + k0 + fs * 8);
        acc[n] = __builtin_amdgcn_mfma_f32_16x16x32_bf16(af, bf, acc[n], 0, 0, 0);
      }
    }
    const int c0 = w * 32 + fr, c1 = c0 + 16;
    const float b0 = b1b[c0], b1 = b1b[c1];
    const float w0 = w2[c0], w1 = w2[c1];
    float part[4];
#pragma unroll
    for (int j = 0; j < 4; ++j) {
      const float d0 = fmaxf(acc[0][j] + b0, 0.f);
      const float d1 = fmaxf(acc[1][j] + b1, 0.f);
      part[j] = d0 * w0 + d1 * w1;
#pragma unroll
      for (int m = 1; m <= 8; m <<= 1) part[j] += __shfl_xor(part[j], m, 64);
    }
    if (fr == 0) {
#pragma unroll
      for (int j = 0; j < 4; ++j) red[w * 16 + fs * 4 + j] = part[j];
    }
    __syncthreads();
    if (t < 16) {
      const float S = red[t] + red[16 + t] + red[32 + t] + red[48 + t] + b2b[0];
      float sgm = 1.f / (1.f + __expf(-S));
      sgm = fminf(fmaxf(sgm, 1e-6f), 1.f - 1e-6f);
      beta[rb + t] = sgm;
    }
  }
}

// ---------------- launch ----------------
extern "C" void kernel_launch(void* const* d_in, const int* in_sizes, int n_in,
                              void* d_out, int out_size, void* d_ws, size_t ws_size,
                              hipStream_t stream) {
  const int N = 2048, D = 256, FF = 1024, L = 4;

  const float* x     = (const float*)d_in[0];
  const int*   batch = (const int*)d_in[2];
  const float* Wi    = (const float*)d_in[3];
  const float* bi    = (const float*)d_in[4];
  const float* qkv_w = (const float*)d_in[5];
  const float* qkv_b = (const float*)d_in[6];
  const float* out_w = (const float*)d_in[7];
  const float* out_b = (const float*)d_in[8];
  const float* ff1_w = (const float*)d_in[9];
  const float* ff1_b = (const float*)d_in[10];
  const float* ff2_w = (const float*)d_in[11];
  const float* ff2_b = (const float*)d_in[12];
  const float* ln1_s = (const float*)d_in[13];
  const float* ln1_b = (const float*)d_in[14];
  const float* ln2_s = (const float*)d_in[15];
  const float* ln2_b = (const float*)d_in[16];
  const float* lat_w = (const float*)d_in[17];
  const float* lat_b = (const float*)d_in[18];
  const float* b1_w  = (const float*)d_in[19];
  const float* b1_b  = (const float*)d_in[20];
  const float* b2_w  = (const float*)d_in[21];
  const float* b2_b  = (const float*)d_in[22];

  float* ws = (float*)d_ws;
  float* h      = ws;                              // N*D f32
  float* tmp    = h + (size_t)N * D;               // 4*N*D f32 (ff2 split-K partials)
  int*  starts  = (int*)(tmp + (size_t)4 * N * D); // 32 ints
  int*  meta    = starts + 32;                     // 448 ints
  short* hb     = (short*)(meta + 448);            // N*D bf16
  short* qkvb   = hb + (size_t)N * D;              // N*3D bf16 (V cols unused)
  short* ffb    = qkvb + (size_t)N * 3 * D;        // N*FF bf16
  short* vtg    = ffb + (size_t)N * FF;            // 256*2048 bf16 (V^T per layer)
  short* qkv_t  = vtg + (size_t)256 * 2048;
  short* out_t  = qkv_t + (size_t)L * 768 * 256;
  short* ff1_t  = out_t + (size_t)L * 256 * 256;
  short* ff2_t  = ff1_t + (size_t)L * 1024 * 256;
  short* b1_t   = ff2_t + (size_t)L * 256 * 1024;
  short* lat_t  = b1_t + (size_t)128 * 256;

  float* beta_out = (float*)d_out;
  float* lat_out  = beta_out + N;

  pack_inproj<<<3113 + 2048, 256, 0, stream>>>(
      qkv_w, out_w, ff1_w, ff2_w, b1_w, lat_w,
      qkv_t, out_t, ff1_t, ff2_t, b1_t, lat_t,
      batch, starts, meta, x, Wi, bi, h, hb);

  for (int l = 0; l < L; ++l) {
    // qkv = h @ qkv_w + b -> bf16 Q,K (+ coalesced V^T)
    gemm_bf16<0, 0, 1><<<dim3(12, 32, 1), 256, 0, stream>>>(
        hb, qkv_t + (size_t)l * 768 * 256, qkv_b + (size_t)l * 768,
        nullptr, qkvb, vtg, N, 768, 256, 256);
    // attention + out-proj + residual + LN1
    attn_fused<<<144, 512, 0, stream>>>(
        qkvb, vtg, meta, out_t + (size_t)l * 256 * 256, out_b + (size_t)l * 256,
        ln1_s + (size_t)l * D, ln1_b + (size_t)l * D, h, hb);
    // ff1 = relu(h @ ff1_w + b) -> bf16
    gemm_bf16<1, 0, 0><<<dim3(16, 32, 1), 256, 0, stream>>>(
        hb, ff1_t + (size_t)l * FF * 256, ff1_b + (size_t)l * FF,
        nullptr, ffb, nullptr, N, FF, 256, 256);
    // ff2 split-K=4 -> f32 partials
    gemm_bf16<0, 4, 0><<<dim3(4, 32, 4), 256, 0, stream>>>(
        ffb, ff2_t + (size_t)l * 256 * FF, ff2_b + (size_t)l * 256,
        tmp, nullptr, nullptr, N, 256, 1024, 256);
    // residual + 4 partials + LN2
    ln_kernel<4><<<N / 4, 256, 0, stream>>>(
        h, tmp, ln2_s + (size_t)l * D, ln2_b + (size_t)l * D, h, hb);
  }

  heads_kernel<<<160, 256, 0, stream>>>(hb, lat_t, lat_b, lat_out,
                                        b1_t, b1_b, b2_w, b2_b, beta_out);
}